// Round 11
// baseline (232.662 us; speedup 1.0000x reference)
//
#include <hip/hip_runtime.h>
#include <hip/hip_bf16.h>

// B=32, S=480, D=512, H=8, dk=64. Outputs: out[32,480,512] fp32,
// attn_mean[32,480,480] fp32, concatenated in d_out.
//
// Pipeline (bf16 MFMA 16x16x32), 6 launches:
//  1. cvt_xw     : x fp32->bf16 (blocks <7680) + w* transpose (blocks >=7680)
//  2. qkv_gemm   : 64x128 TILE (was 128x128): LDS 48KB dbuf -> 3 blocks/CU,
//                  12 waves/CU (+50% TLP; kernel is latency-bound: MfmaUtil
//                  19/VALU 17/HBM 25/Occ 18 at 2 blocks/CU). 2-phase dbuf.
//                  z<2 -> q/k gemm (x<240), z==2 -> V tiled gemm (x=b*8+ddt).
//  3. cvt_rbt    : rel_bias*log2e -> paired rbt (MUST follow qkv: aliases xb)
//  4. flash_attn : balanced pairing slot s<7 -> {s,13-s}, s==7 -> {14};
//                  straight loop, exp2, diag-only mask, cvt_pk, setprio.
//                  P tiles fp16 -> pscr coalesced; cst = 1/lsum [bh][i].
//  5. attn_mean_p: streaming mean: read pscr (8 heads) * rinv -> fp32.
//  6. out_gemm   : ctx @ woT + bo -> fp32, 128x128 2-phase dbuf.

typedef unsigned short ushort_t;
typedef __attribute__((ext_vector_type(8))) short short8;
typedef __attribute__((ext_vector_type(4))) float floatx4;
typedef __attribute__((ext_vector_type(2))) __fp16 half2v;

#define NB 32
#define NS 480
#define ND 512
#define NH 8
#define NDK 64
#define MAXLEN 500
#define PSTR 36   // sP row stride (ushorts): b128 frag reads <=2-way bank alias
#define SCL 0.18033688f  // 0.125 * log2(e)

__device__ __forceinline__ ushort_t f2bf(float f) {
  union { float f; unsigned u; } v; v.f = f;
  unsigned r = v.u + 0x7FFFu + ((v.u >> 16) & 1u);
  return (ushort_t)(r >> 16);
}

#define GLOAD_LDS16(g, l)                                                      \
  __builtin_amdgcn_global_load_lds(                                            \
      (const __attribute__((address_space(1))) void*)(g),                      \
      (__attribute__((address_space(3))) void*)(l), 16, 0, 0)

// ---------------------------------------------------------------- cvt_xw
// blocks [0,7680): x fp32->bf16 vectorized. blocks [7680,8704): w transpose.
__global__ __launch_bounds__(256)
void cvt_xw(const float* __restrict__ x, const float* __restrict__ wq,
            const float* __restrict__ wk, const float* __restrict__ wv,
            const float* __restrict__ wo, ushort_t* __restrict__ xb,
            ushort_t* __restrict__ wqT, ushort_t* __restrict__ wkT,
            ushort_t* __restrict__ wvT, ushort_t* __restrict__ woT) {
  __shared__ float t[32][33];
  const int bid = blockIdx.x;
  if (bid < 7680) {
    int idx = bid * 256 + threadIdx.x;
    float4 v = ((const float4*)x)[idx];
    ushort4 o;
    o.x = f2bf(v.x); o.y = f2bf(v.y); o.z = f2bf(v.z); o.w = f2bf(v.w);
    ((ushort4*)xb)[idx] = o;
    return;
  }
  const int q = bid - 7680;
  const int z = q >> 8;
  const float* w = (z == 0) ? wq : (z == 1) ? wk : (z == 2) ? wv : wo;
  ushort_t* wT = (z == 0) ? wqT : (z == 1) ? wkT : (z == 2) ? wvT : woT;
  int k0 = (q & 15) * 32, n0 = ((q >> 4) & 15) * 32;
  int tx = threadIdx.x & 31, ty = threadIdx.x >> 5;
#pragma unroll
  for (int yy = 0; yy < 4; ++yy)
    t[ty + yy * 8][tx] = w[(k0 + ty + yy * 8) * ND + n0 + tx];
  __syncthreads();
#pragma unroll
  for (int yy = 0; yy < 4; ++yy)
    wT[(n0 + ty + yy * 8) * ND + k0 + tx] = f2bf(t[tx][ty + yy * 8]);
}

// ---------------------------------------------------------------- cvt_rbt
__global__ void cvt_rbt(const float* __restrict__ rel_bias, float* __restrict__ rbt) {
  int kt = blockIdx.x, ib = blockIdx.y, h = blockIdx.z;
  int lm = threadIdx.x & 15, ii = threadIdx.x >> 4;
  int i = ib * 16 + ii;
  float f0 = rel_bias[((size_t)h * MAXLEN + i) * MAXLEN + kt * 32 + lm] * 1.44269504f;
  float f1 = rel_bias[((size_t)h * MAXLEN + i) * MAXLEN + kt * 32 + 16 + lm] * 1.44269504f;
  float2 o = {f0, f1};
  *(float2*)&rbt[(((size_t)h * 15 + kt) * NS + i) * 32 + 2 * lm] = o;
}

// ---------------------------------------------------------------- qkv_gemm
// 64x128 tile, 2-phase dbuf, 48KB LDS -> 3 blocks/CU.
// z in {0,1}: q/k gemm, row-blocks x<240 (M = B*S = 15360).
// z == 2   : V tiled gemm, b = x>>3, ddt = x&7.
__global__ __launch_bounds__(256)
void qkv_gemm(const ushort_t* __restrict__ xb,
              const ushort_t* __restrict__ wqT, const ushort_t* __restrict__ wkT,
              const ushort_t* __restrict__ wvT,
              const float* __restrict__ bq, const float* __restrict__ bk,
              const float* __restrict__ bv,
              ushort_t* __restrict__ qb, ushort_t* __restrict__ kb,
              ushort_t* __restrict__ vtil) {
  __shared__ __align__(16) ushort_t sA[2][64 * 64];
  __shared__ __align__(16) ushort_t sB[2][128 * 64];
  const int tid = threadIdx.x;
  const int wid = tid >> 6, lane = tid & 63;
  const int lm = lane & 15, quad = lane >> 4;
  const int wc = wid;  // 4 col-groups of 32
  const int z = blockIdx.z;

  floatx4 zero4 = {0.f, 0.f, 0.f, 0.f};
  floatx4 acc[4][2];
#pragma unroll
  for (int i = 0; i < 4; ++i)
#pragma unroll
    for (int j = 0; j < 2; ++j) acc[i][j] = zero4;

  // staging geometry: slot li = c*256+tid; row = li>>3, kc = li&7
  const int skc = tid & 7;

  const ushort_t* Asrc;
  const ushort_t* Bsrc;
  int row0, col0, bidx = 0;
  bool bclamp;
  if (z < 2) {
    if (blockIdx.x >= 240) return;
    row0 = blockIdx.x * 64;
    col0 = blockIdx.y * 128;
    Asrc = xb;
    Bsrc = (z == 0) ? wqT : wkT;
    bclamp = false;
  } else {
    bidx = blockIdx.x >> 3;
    row0 = (blockIdx.x & 7) * 64;  // dd
    col0 = blockIdx.y * 128;       // s
    Asrc = wvT;
    Bsrc = xb + (size_t)bidx * NS * ND;
    bclamp = true;
  }

  // prologue: stage k0=0 into buf 0
#pragma unroll
  for (int c = 0; c < 2; ++c) {
    int row = (c * 256 + tid) >> 3;
    int kcs = skc ^ (row & 7);
    GLOAD_LDS16(Asrc + (row0 + row) * ND + kcs * 8, &sA[0][(c * 256 + wid * 64) * 8]);
  }
#pragma unroll
  for (int c = 0; c < 4; ++c) {
    int row = (c * 256 + tid) >> 3;
    int kcs = skc ^ (row & 7);
    int sr = bclamp ? min(col0 + row, NS - 1) : (col0 + row);
    GLOAD_LDS16(Bsrc + sr * ND + kcs * 8, &sB[0][(c * 256 + wid * 64) * 8]);
  }
  __syncthreads();

  int buf = 0;
  for (int t = 0; t < 8; ++t) {
    if (t < 7) {
      int k0n = (t + 1) * 64;
#pragma unroll
      for (int c = 0; c < 2; ++c) {
        int row = (c * 256 + tid) >> 3;
        int kcs = skc ^ (row & 7);
        GLOAD_LDS16(Asrc + (row0 + row) * ND + k0n + kcs * 8,
                    &sA[buf ^ 1][(c * 256 + wid * 64) * 8]);
      }
#pragma unroll
      for (int c = 0; c < 4; ++c) {
        int row = (c * 256 + tid) >> 3;
        int kcs = skc ^ (row & 7);
        int sr = bclamp ? min(col0 + row, NS - 1) : (col0 + row);
        GLOAD_LDS16(Bsrc + sr * ND + k0n + kcs * 8,
                    &sB[buf ^ 1][(c * 256 + wid * 64) * 8]);
      }
    }
#pragma unroll
    for (int h2 = 0; h2 < 2; ++h2) {
      short8 a[4], b[2];
#pragma unroll
      for (int i = 0; i < 4; ++i) {
        int row = i * 16 + lm;
        a[i] = *(const short8*)&sA[buf][row * 64 + (((h2 << 2) | quad) ^ (lm & 7)) * 8];
      }
#pragma unroll
      for (int j = 0; j < 2; ++j) {
        int row = wc * 32 + j * 16 + lm;
        b[j] = *(const short8*)&sB[buf][row * 64 + (((h2 << 2) | quad) ^ (lm & 7)) * 8];
      }
#pragma unroll
      for (int i = 0; i < 4; ++i)
#pragma unroll
        for (int j = 0; j < 2; ++j)
          acc[i][j] = __builtin_amdgcn_mfma_f32_16x16x32_bf16(a[i], b[j], acc[i][j], 0, 0, 0);
    }
    __syncthreads();
    buf ^= 1;
  }

  if (z < 2) {
    const float* bias = (z == 0) ? bq : bk;
    float bsv[2];
#pragma unroll
    for (int j = 0; j < 2; ++j) bsv[j] = bias[col0 + wc * 32 + j * 16 + lm];

#pragma unroll
    for (int i = 0; i < 4; ++i)
#pragma unroll
      for (int j = 0; j < 2; ++j)
#pragma unroll
        for (int r = 0; r < 4; ++r) {
          int m = row0 + i * 16 + quad * 4 + r;
          int n = col0 + wc * 32 + j * 16 + lm;
          float val = acc[i][j][r] + bsv[j];
          int bb = m / NS, s = m - bb * NS;
          int h = n >> 6, d = n & 63;
          ushort_t o = f2bf(val);
          if (z == 0) qb[((bb * NH + h) * NS + s) * NDK + d] = o;
          else        kb[((bb * NH + h) * NS + s) * NDK + d] = o;
        }
  } else {
#pragma unroll
    for (int i = 0; i < 4; ++i)
#pragma unroll
      for (int r = 0; r < 4; ++r) {
        int m = row0 + i * 16 + quad * 4 + r;  // dd = h*64 + d
        float bias = bv[m];
#pragma unroll
        for (int j = 0; j < 2; ++j) {
          int n = col0 + wc * 32 + j * 16 + lm;  // s
          if (n < NS) {
            size_t idx = (((size_t)bidx * NH + (m >> 6)) * 15 + (n >> 5)) * 2048 +
                         (m & 63) * 32 + (n & 31);
            vtil[idx] = f2bf(acc[i][j][r] + bias);
          }
        }
      }
  }
}

// ---------------------------------------------------------------- flash_attn
// grid (256 bh, 2). slot = y*4+wid in 0..7; slot<7 -> tiles {slot, 13-slot},
// slot==7 -> {14}: every wave runs exactly 15 kt-iterations (load-balanced).
__global__ __launch_bounds__(256)
void flash_attn(const ushort_t* __restrict__ qb, const ushort_t* __restrict__ kb,
                const ushort_t* __restrict__ vtil, const float* __restrict__ rbt,
                ushort_t* __restrict__ ctxb, float* __restrict__ cst,
                uint4* __restrict__ pscr) {
  const int bh = blockIdx.x;
  const int b = bh >> 3, h = bh & 7;
  const int tid = threadIdx.x;
  const int wid = tid >> 6, lane = tid & 63;
  const int lm = lane & 15, quad = lane >> 4;

  __shared__ __align__(16) ushort_t sP[4][32 * PSTR];

  const int slot = blockIdx.y * 4 + wid;  // 0..7
  const int tA = (slot == 7) ? 14 : slot;
  const int tB = (slot == 7) ? -1 : 13 - slot;

  const ushort_t* qh = qb + (size_t)bh * NS * NDK;
  const ushort_t* kh = kb + (size_t)bh * NS * NDK;
  const ushort_t* vb = vtil + (size_t)bh * 15 * 2048;
  const float* rb = rbt + (size_t)h * 15 * NS * 32;

#pragma unroll 1
  for (int ti = 0; ti < 2; ++ti) {
    const int t = (ti == 0) ? tA : tB;
    if (t < 0) break;
    const int nkt = t + 1;
    uint4* pp = pscr + ((size_t)(bh * 120 + (t * (t + 1)) / 2)) * 128 + lane;

    short8 aq[2][2];
#pragma unroll
    for (int g = 0; g < 2; ++g) {
      aq[g][0] = *(const short8*)&qh[(t * 32 + g * 16 + lm) * NDK + quad * 8];
      aq[g][1] = *(const short8*)&qh[(t * 32 + g * 16 + lm) * NDK + 32 + quad * 8];
    }

    float lsum[2][4];
    floatx4 O[2][4];
    floatx4 zero4 = {0.f, 0.f, 0.f, 0.f};
#pragma unroll
    for (int g = 0; g < 2; ++g) {
#pragma unroll
      for (int r = 0; r < 4; ++r) lsum[g][r] = 0.f;
#pragma unroll
      for (int jd = 0; jd < 4; ++jd) O[g][jd] = zero4;
    }

    for (int kt = 0; kt < nkt; ++kt) {
      const int kvA = kt * 32 + lm;
      const int kvB = kvA + 16;
      short8 bkA0 = *(const short8*)&kh[kvA * NDK + quad * 8];
      short8 bkA1 = *(const short8*)&kh[kvA * NDK + 32 + quad * 8];
      short8 bkB0 = *(const short8*)&kh[kvB * NDK + quad * 8];
      short8 bkB1 = *(const short8*)&kh[kvB * NDK + 32 + quad * 8];
      short8 bv2[4];
#pragma unroll
      for (int jd = 0; jd < 4; ++jd)
        bv2[jd] = *(const short8*)&vb[kt * 2048 + (jd * 16 + lm) * 32 + quad * 8];
      float2 bb[2][4];
#pragma unroll
      for (int g = 0; g < 2; ++g)
#pragma unroll
        for (int r = 0; r < 4; ++r) {
          int i = t * 32 + g * 16 + quad * 4 + r;
          bb[g][r] = *(const float2*)&rb[((size_t)kt * NS + i) * 32 + 2 * lm];
        }

      floatx4 sA[2], sB[2];
      __builtin_amdgcn_s_setprio(1);
#pragma unroll
      for (int g = 0; g < 2; ++g) {
        floatx4 s = zero4;
        s = __builtin_amdgcn_mfma_f32_16x16x32_bf16(aq[g][0], bkA0, s, 0, 0, 0);
        s = __builtin_amdgcn_mfma_f32_16x16x32_bf16(aq[g][1], bkA1, s, 0, 0, 0);
        sA[g] = s;
        s = zero4;
        s = __builtin_amdgcn_mfma_f32_16x16x32_bf16(aq[g][0], bkB0, s, 0, 0, 0);
        s = __builtin_amdgcn_mfma_f32_16x16x32_bf16(aq[g][1], bkB1, s, 0, 0, 0);
        sB[g] = s;
      }
      __builtin_amdgcn_s_setprio(0);

      const bool diag = (kt == t);  // wave-uniform
#pragma unroll
      for (int g = 0; g < 2; ++g) {
        unsigned pw[4];
#pragma unroll
        for (int r = 0; r < 4; ++r) {
          float p0 = __builtin_amdgcn_exp2f(fmaf(sA[g][r], SCL, bb[g][r].x));
          float p1 = __builtin_amdgcn_exp2f(fmaf(sB[g][r], SCL, bb[g][r].y));
          if (diag) {
            int i = t * 32 + g * 16 + quad * 4 + r;
            if (kvA > i) p0 = 0.f;
            if (kvB > i) p1 = 0.f;
          }
          lsum[g][r] += p0 + p1;
          unsigned pk;
          asm("v_cvt_pk_bf16_f32 %0, %1, %2" : "=v"(pk) : "v"(p0), "v"(p1));
          sP[wid][(g * 16 + quad * 4 + r) * PSTR + lm] = (ushort_t)(pk & 0xffffu);
          sP[wid][(g * 16 + quad * 4 + r) * PSTR + 16 + lm] = (ushort_t)(pk >> 16);
          half2v hp = __builtin_amdgcn_cvt_pkrtz(p0, p1);
          pw[r] = *(unsigned*)&hp;
        }
        uint4 pq = {pw[0], pw[1], pw[2], pw[3]};
        pp[(size_t)kt * 128 + g * 64] = pq;  // fire-and-forget, 1KB/instr
      }

      __builtin_amdgcn_s_setprio(1);
#pragma unroll
      for (int g = 0; g < 2; ++g) {
        short8 ap = *(const short8*)&sP[wid][(g * 16 + lm) * PSTR + quad * 8];
#pragma unroll
        for (int jd = 0; jd < 4; ++jd)
          O[g][jd] = __builtin_amdgcn_mfma_f32_16x16x32_bf16(ap, bv2[jd], O[g][jd], 0, 0, 0);
      }
      __builtin_amdgcn_s_setprio(0);
    }

#pragma unroll
    for (int off = 1; off < 16; off <<= 1)
#pragma unroll
      for (int g = 0; g < 2; ++g)
#pragma unroll
        for (int r = 0; r < 4; ++r) lsum[g][r] += __shfl_xor(lsum[g][r], off, 64);

#pragma unroll
    for (int g = 0; g < 2; ++g) {
      float rinv[4];
#pragma unroll
      for (int r = 0; r < 4; ++r) rinv[r] = 1.f / lsum[g][r];
#pragma unroll
      for (int jd = 0; jd < 4; ++jd)
#pragma unroll
        for (int r = 0; r < 4; ++r) {
          int i = t * 32 + g * 16 + quad * 4 + r;
          ctxb[((size_t)b * NS + i) * ND + h * NDK + jd * 16 + lm] =
              f2bf(O[g][jd][r] * rinv[r]);
        }
      if (lm == 0) {
#pragma unroll
        for (int r = 0; r < 4; ++r) {
          int i = t * 32 + g * 16 + quad * 4 + r;
          cst[(size_t)bh * NS + i] = rinv[r];
        }
      }
    }
  }
}

// ---------------------------------------------------------------- attn_mean_p
__global__ __launch_bounds__(64)
void attn_mean_p(const uint4* __restrict__ pscr, const float* __restrict__ cst,
                 float* __restrict__ am) {
  const int b = blockIdx.x, t = blockIdx.y, kt = blockIdx.z;
  const int lane = threadIdx.x;
  const int lm = lane & 15, quad = lane >> 4;
  float* outp = am + ((size_t)b * NS + t * 32) * NS + (size_t)kt * 32;
  if (kt > t) {
#pragma unroll
    for (int g = 0; g < 2; ++g)
#pragma unroll
      for (int r = 0; r < 4; ++r) {
        int row = g * 16 + quad * 4 + r;
        outp[(size_t)row * NS + lm] = 0.f;
        outp[(size_t)row * NS + 16 + lm] = 0.f;
      }
    return;
  }
  const int m = (t * (t + 1)) / 2 + kt;
  float a0[2][4], a1[2][4];
#pragma unroll
  for (int g = 0; g < 2; ++g)
#pragma unroll
    for (int r = 0; r < 4; ++r) { a0[g][r] = 0.f; a1[g][r] = 0.f; }

#pragma unroll
  for (int h = 0; h < NH; ++h) {
    const uint4* pp = pscr + ((size_t)(b * NH + h) * 120 + m) * 128 + lane;
    uint4 q0 = pp[0];        // g=0: rows quad*4..+3 of 0..15, cols lm/16+lm
    uint4 q1 = pp[64];       // g=1
    unsigned pu[8] = {q0.x, q0.y, q0.z, q0.w, q1.x, q1.y, q1.z, q1.w};
    const float* cp = cst + (size_t)(b * NH + h) * NS + t * 32 + quad * 4;
    float4 rv0 = *(const float4*)cp;
    float4 rv1 = *(const float4*)(cp + 16);
    float rv[8] = {rv0.x, rv0.y, rv0.z, rv0.w, rv1.x, rv1.y, rv1.z, rv1.w};
#pragma unroll
    for (int g = 0; g < 2; ++g)
#pragma unroll
      for (int r = 0; r < 4; ++r) {
        half2v hp = *(half2v*)&pu[g * 4 + r];
        a0[g][r] = fmaf((float)hp.x, rv[g * 4 + r], a0[g][r]);
        a1[g][r] = fmaf((float)hp.y, rv[g * 4 + r], a1[g][r]);
      }
  }

#pragma unroll
  for (int g = 0; g < 2; ++g)
#pragma unroll
    for (int r = 0; r < 4; ++r) {
      int row = g * 16 + quad * 4 + r;
      outp[(size_t)row * NS + lm] = a0[g][r] * 0.125f;
      outp[(size_t)row * NS + 16 + lm] = a1[g][r] * 0.125f;
    }
}

// ---------------------------------------------------------------- out_gemm
// ctx @ woT + bo, 2-phase double-buffered LDS staging.
__global__ __launch_bounds__(256)
void out_gemm(const ushort_t* __restrict__ ctxb, const ushort_t* __restrict__ woT,
              const float* __restrict__ bo, float* __restrict__ out) {
  __shared__ __align__(16) ushort_t sA[2][128 * 64];
  __shared__ __align__(16) ushort_t sB[2][128 * 64];
  const int tid = threadIdx.x;
  const int wid = tid >> 6, lane = tid & 63;
  const int lm = lane & 15, quad = lane >> 4;
  const int wr = wid >> 1, wc = wid & 1;
  const int row0 = blockIdx.x * 128;
  const int col0 = blockIdx.y * 128;
  const int srow_ = tid >> 3, skc = tid & 7;
  const int skcs = skc ^ (srow_ & 7);

  floatx4 zero4 = {0.f, 0.f, 0.f, 0.f};
  floatx4 acc[4][4];
#pragma unroll
  for (int i = 0; i < 4; ++i)
#pragma unroll
    for (int j = 0; j < 4; ++j) acc[i][j] = zero4;

#pragma unroll
  for (int c = 0; c < 4; ++c) {
    int row = c * 32 + srow_;
    GLOAD_LDS16(ctxb + (row0 + row) * ND + skcs * 8, &sA[0][(c * 256 + wid * 64) * 8]);
    GLOAD_LDS16(woT + (col0 + row) * ND + skcs * 8, &sB[0][(c * 256 + wid * 64) * 8]);
  }
  __syncthreads();

  int buf = 0;
  for (int t = 0; t < 8; ++t) {
    if (t < 7) {
      int k0n = (t + 1) * 64;
#pragma unroll
      for (int c = 0; c < 4; ++c) {
        int row = c * 32 + srow_;
        GLOAD_LDS16(ctxb + (row0 + row) * ND + k0n + skcs * 8,
                    &sA[buf ^ 1][(c * 256 + wid * 64) * 8]);
        GLOAD_LDS16(woT + (col0 + row) * ND + k0n + skcs * 8,
                    &sB[buf ^ 1][(c * 256 + wid * 64) * 8]);
      }
    }
#pragma unroll
    for (int h2 = 0; h2 < 2; ++h2) {
      short8 a[4], b[4];
#pragma unroll
      for (int i = 0; i < 4; ++i) {
        int row = wr * 64 + i * 16 + lm;
        a[i] = *(const short8*)&sA[buf][row * 64 + (((h2 << 2) | quad) ^ (lm & 7)) * 8];
      }
#pragma unroll
      for (int j = 0; j < 4; ++j) {
        int row = wc * 64 + j * 16 + lm;
        b[j] = *(const short8*)&sB[buf][row * 64 + (((h2 << 2) | quad) ^ (lm & 7)) * 8];
      }
#pragma unroll
      for (int i = 0; i < 4; ++i)
#pragma unroll
        for (int j = 0; j < 4; ++j)
          acc[i][j] = __builtin_amdgcn_mfma_f32_16x16x32_bf16(a[i], b[j], acc[i][j], 0, 0, 0);
    }
    __syncthreads();
    buf ^= 1;
  }

  float bsv[4];
#pragma unroll
  for (int j = 0; j < 4; ++j) bsv[j] = bo[col0 + wc * 64 + j * 16 + lm];

#pragma unroll
  for (int i = 0; i < 4; ++i)
#pragma unroll
    for (int j = 0; j < 4; ++j)
#pragma unroll
      for (int r = 0; r < 4; ++r) {
        int m = row0 + wr * 64 + i * 16 + quad * 4 + r;
        int n = col0 + wc * 64 + j * 16 + lm;
        out[m * ND + n] = acc[i][j][r] + bsv[j];
      }
}

// ---------------------------------------------------------------- launch
extern "C" void kernel_launch(void* const* d_in, const int* in_sizes, int n_in,
                              void* d_out, int out_size, void* d_ws, size_t ws_size,
                              hipStream_t stream) {
  const float* x  = (const float*)d_in[0];
  const float* wq = (const float*)d_in[1];
  const float* bq = (const float*)d_in[2];
  const float* wk = (const float*)d_in[3];
  const float* bk = (const float*)d_in[4];
  const float* wv = (const float*)d_in[5];
  const float* bv = (const float*)d_in[6];
  const float* wo = (const float*)d_in[7];
  const float* bo = (const float*)d_in[8];
  const float* rel_bias = (const float*)d_in[9];

  char* w = (char*)d_ws;
  ushort_t* xb  = (ushort_t*)w;                       // 15,728,640 B
  ushort_t* wqT = (ushort_t*)(w + 15728640);          // 4 x 524,288 B
  ushort_t* wkT = wqT + 262144;
  ushort_t* wvT = wkT + 262144;
  ushort_t* woT = wvT + 262144;
  ushort_t* qb  = (ushort_t*)(w + 15728640 + 4 * 524288);
  ushort_t* kb  = qb + 7864320;
  ushort_t* vtil = kb + 7864320;                      // tiled V
  ushort_t* ctxb = vtil + 7864320;
  float* cstat = (float*)(w + 80740352);              // rinv [bh][i], 491,520 B
  uint4* pscr = (uint4*)(w + 81264640);               // P scratch, 62,914,560 B
  // rbt (14,745,600 B) aliases xb — xb is dead after qkv_gemm
  float* rbt = (float*)w;

  float* out0 = (float*)d_out;        // [32,480,512]
  float* attn_mean = out0 + 7864320;  // [32,480,480]

  cvt_xw<<<dim3(8704), dim3(256), 0, stream>>>(x, wq, wk, wv, wo, xb, wqT, wkT, wvT, woT);
  qkv_gemm<<<dim3(256, 4, 3), dim3(256), 0, stream>>>(xb, wqT, wkT, wvT, bq, bk, bv,
                                                      qb, kb, vtil);
  cvt_rbt<<<dim3(15, 30, 8), dim3(256), 0, stream>>>(rel_bias, rbt);
  flash_attn<<<dim3(256, 2), dim3(256), 0, stream>>>(qb, kb, vtil, rbt, ctxb, cstat, pscr);
  attn_mean_p<<<dim3(32, 15, 15), dim3(64), 0, stream>>>(pscr, cstat, attn_mean);
  out_gemm<<<dim3(120, 4), dim3(256), 0, stream>>>(ctxb, woT, bo, out0);
}

// Round 12
// 231.347 us; speedup vs baseline: 1.0057x; 1.0057x over previous
//
#include <hip/hip_runtime.h>
#include <hip/hip_bf16.h>

// B=32, S=480, D=512, H=8, dk=64. Outputs: out[32,480,512] fp32,
// attn_mean[32,480,480] fp32, concatenated in d_out.
//
// Pipeline (bf16 MFMA 16x16x32), 6 launches:
//  1. cvt_xw     : x fp32->bf16 (blocks <7680) + w* transpose (blocks >=7680)
//  2. qkv_gemm   : 128x128 tile, BK=32, 2-phase dbuf, 32KB LDS -> 5 blocks/CU
//                  (BK=64 was 64KB -> 2 blocks, latency-bound at 19% MfmaUtil;
//                  64x128 tile raised FETCH 51->87MB: tile shrink trades bytes
//                  for TLP at a loss — shrink K instead, bytes unchanged).
//  3. cvt_rbt    : rel_bias*log2e -> paired rbt (MUST follow qkv: aliases xb)
//  4. flash_attn : balanced pairing slot s<7 -> {s,13-s}, s==7 -> {14};
//                  straight loop, exp2, diag-only mask, cvt_pk, setprio.
//                  P tiles fp16 -> pscr coalesced; cst = 1/lsum [bh][i].
//  5. attn_mean_p: streaming mean: read pscr (8 heads) * rinv -> fp32.
//  6. out_gemm   : ctx @ woT + bo -> fp32, 128x128 BK=64 2-phase dbuf.

typedef unsigned short ushort_t;
typedef __attribute__((ext_vector_type(8))) short short8;
typedef __attribute__((ext_vector_type(4))) float floatx4;
typedef __attribute__((ext_vector_type(2))) __fp16 half2v;

#define NB 32
#define NS 480
#define ND 512
#define NH 8
#define NDK 64
#define MAXLEN 500
#define PSTR 36   // sP row stride (ushorts): b128 frag reads <=2-way bank alias
#define SCL 0.18033688f  // 0.125 * log2(e)

__device__ __forceinline__ ushort_t f2bf(float f) {
  union { float f; unsigned u; } v; v.f = f;
  unsigned r = v.u + 0x7FFFu + ((v.u >> 16) & 1u);
  return (ushort_t)(r >> 16);
}

#define GLOAD_LDS16(g, l)                                                      \
  __builtin_amdgcn_global_load_lds(                                            \
      (const __attribute__((address_space(1))) void*)(g),                      \
      (__attribute__((address_space(3))) void*)(l), 16, 0, 0)

// ---------------------------------------------------------------- cvt_xw
// blocks [0,7680): x fp32->bf16 vectorized. blocks [7680,8704): w transpose.
__global__ __launch_bounds__(256)
void cvt_xw(const float* __restrict__ x, const float* __restrict__ wq,
            const float* __restrict__ wk, const float* __restrict__ wv,
            const float* __restrict__ wo, ushort_t* __restrict__ xb,
            ushort_t* __restrict__ wqT, ushort_t* __restrict__ wkT,
            ushort_t* __restrict__ wvT, ushort_t* __restrict__ woT) {
  __shared__ float t[32][33];
  const int bid = blockIdx.x;
  if (bid < 7680) {
    int idx = bid * 256 + threadIdx.x;
    float4 v = ((const float4*)x)[idx];
    ushort4 o;
    o.x = f2bf(v.x); o.y = f2bf(v.y); o.z = f2bf(v.z); o.w = f2bf(v.w);
    ((ushort4*)xb)[idx] = o;
    return;
  }
  const int q = bid - 7680;
  const int z = q >> 8;
  const float* w = (z == 0) ? wq : (z == 1) ? wk : (z == 2) ? wv : wo;
  ushort_t* wT = (z == 0) ? wqT : (z == 1) ? wkT : (z == 2) ? wvT : woT;
  int k0 = (q & 15) * 32, n0 = ((q >> 4) & 15) * 32;
  int tx = threadIdx.x & 31, ty = threadIdx.x >> 5;
#pragma unroll
  for (int yy = 0; yy < 4; ++yy)
    t[ty + yy * 8][tx] = w[(k0 + ty + yy * 8) * ND + n0 + tx];
  __syncthreads();
#pragma unroll
  for (int yy = 0; yy < 4; ++yy)
    wT[(n0 + ty + yy * 8) * ND + k0 + tx] = f2bf(t[tx][ty + yy * 8]);
}

// ---------------------------------------------------------------- cvt_rbt
__global__ void cvt_rbt(const float* __restrict__ rel_bias, float* __restrict__ rbt) {
  int kt = blockIdx.x, ib = blockIdx.y, h = blockIdx.z;
  int lm = threadIdx.x & 15, ii = threadIdx.x >> 4;
  int i = ib * 16 + ii;
  float f0 = rel_bias[((size_t)h * MAXLEN + i) * MAXLEN + kt * 32 + lm] * 1.44269504f;
  float f1 = rel_bias[((size_t)h * MAXLEN + i) * MAXLEN + kt * 32 + 16 + lm] * 1.44269504f;
  float2 o = {f0, f1};
  *(float2*)&rbt[(((size_t)h * 15 + kt) * NS + i) * 32 + 2 * lm] = o;
}

// ---------------------------------------------------------------- qkv_gemm
// 128x128 tile, BK=32, 2-phase dbuf, 32KB LDS -> 5 blocks/CU.
// z in {0,1}: q/k gemm (x<120). z==2: V tiled gemm, b=x>>2, ddt=x&3.
__global__ __launch_bounds__(256)
void qkv_gemm(const ushort_t* __restrict__ xb,
              const ushort_t* __restrict__ wqT, const ushort_t* __restrict__ wkT,
              const ushort_t* __restrict__ wvT,
              const float* __restrict__ bq, const float* __restrict__ bk,
              const float* __restrict__ bv,
              ushort_t* __restrict__ qb, ushort_t* __restrict__ kb,
              ushort_t* __restrict__ vtil) {
  __shared__ __align__(16) ushort_t sA[2][128 * 32];
  __shared__ __align__(16) ushort_t sB[2][128 * 32];
  const int tid = threadIdx.x;
  const int wid = tid >> 6, lane = tid & 63;
  const int lm = lane & 15, quad = lane >> 4;
  const int wr = wid >> 1, wc = wid & 1;
  const int z = blockIdx.z;

  floatx4 zero4 = {0.f, 0.f, 0.f, 0.f};
  floatx4 acc[4][4];
#pragma unroll
  for (int i = 0; i < 4; ++i)
#pragma unroll
    for (int j = 0; j < 4; ++j) acc[i][j] = zero4;

  // staging geometry: li = c*256+tid; row = li>>2 (0..127), kc = li&3
  const int skc = tid & 3;

  const ushort_t* Asrc;
  const ushort_t* Bsrc;
  int row0, col0, bidx = 0;
  bool bclamp;
  if (z < 2) {
    if (blockIdx.x >= 120) return;
    row0 = blockIdx.x * 128;
    col0 = blockIdx.y * 128;
    Asrc = xb;
    Bsrc = (z == 0) ? wqT : wkT;
    bclamp = false;
  } else {
    bidx = blockIdx.x >> 2;
    row0 = (blockIdx.x & 3) * 128;  // dd
    col0 = blockIdx.y * 128;        // s
    Asrc = wvT;
    Bsrc = xb + (size_t)bidx * NS * ND;
    bclamp = true;
  }

  // prologue: stage k0=0 into buf 0
#pragma unroll
  for (int c = 0; c < 2; ++c) {
    int row = (c * 256 + tid) >> 2;
    int kcs = skc ^ (row & 3);
    GLOAD_LDS16(Asrc + (row0 + row) * ND + kcs * 8, &sA[0][(c * 256 + wid * 64) * 8]);
    int sr = bclamp ? min(col0 + row, NS - 1) : (col0 + row);
    GLOAD_LDS16(Bsrc + sr * ND + kcs * 8, &sB[0][(c * 256 + wid * 64) * 8]);
  }
  __syncthreads();

  int buf = 0;
  for (int t = 0; t < 16; ++t) {
    if (t < 15) {
      int k0n = (t + 1) * 32;
#pragma unroll
      for (int c = 0; c < 2; ++c) {
        int row = (c * 256 + tid) >> 2;
        int kcs = skc ^ (row & 3);
        GLOAD_LDS16(Asrc + (row0 + row) * ND + k0n + kcs * 8,
                    &sA[buf ^ 1][(c * 256 + wid * 64) * 8]);
        int sr = bclamp ? min(col0 + row, NS - 1) : (col0 + row);
        GLOAD_LDS16(Bsrc + sr * ND + k0n + kcs * 8,
                    &sB[buf ^ 1][(c * 256 + wid * 64) * 8]);
      }
    }
    {
      short8 a[4], b[4];
#pragma unroll
      for (int i = 0; i < 4; ++i) {
        int row = wr * 64 + i * 16 + lm;
        a[i] = *(const short8*)&sA[buf][row * 32 + (quad ^ (lm & 3)) * 8];
      }
#pragma unroll
      for (int j = 0; j < 4; ++j) {
        int row = wc * 64 + j * 16 + lm;
        b[j] = *(const short8*)&sB[buf][row * 32 + (quad ^ (lm & 3)) * 8];
      }
#pragma unroll
      for (int i = 0; i < 4; ++i)
#pragma unroll
        for (int j = 0; j < 4; ++j)
          acc[i][j] = __builtin_amdgcn_mfma_f32_16x16x32_bf16(a[i], b[j], acc[i][j], 0, 0, 0);
    }
    __syncthreads();
    buf ^= 1;
  }

  if (z < 2) {
    const float* bias = (z == 0) ? bq : bk;
    float bsv[4];
#pragma unroll
    for (int j = 0; j < 4; ++j) bsv[j] = bias[col0 + wc * 64 + j * 16 + lm];

#pragma unroll
    for (int i = 0; i < 4; ++i)
#pragma unroll
      for (int j = 0; j < 4; ++j)
#pragma unroll
        for (int r = 0; r < 4; ++r) {
          int m = row0 + wr * 64 + i * 16 + quad * 4 + r;
          int n = col0 + wc * 64 + j * 16 + lm;
          float val = acc[i][j][r] + bsv[j];
          int bb = m / NS, s = m - bb * NS;
          int h = n >> 6, d = n & 63;
          ushort_t o = f2bf(val);
          if (z == 0) qb[((bb * NH + h) * NS + s) * NDK + d] = o;
          else        kb[((bb * NH + h) * NS + s) * NDK + d] = o;
        }
  } else {
#pragma unroll
    for (int i = 0; i < 4; ++i)
#pragma unroll
      for (int r = 0; r < 4; ++r) {
        int m = row0 + wr * 64 + i * 16 + quad * 4 + r;  // dd = h*64 + d
        float bias = bv[m];
#pragma unroll
        for (int j = 0; j < 4; ++j) {
          int n = col0 + wc * 64 + j * 16 + lm;  // s
          if (n < NS) {
            size_t idx = (((size_t)bidx * NH + (m >> 6)) * 15 + (n >> 5)) * 2048 +
                         (m & 63) * 32 + (n & 31);
            vtil[idx] = f2bf(acc[i][j][r] + bias);
          }
        }
      }
  }
}

// ---------------------------------------------------------------- flash_attn
// grid (256 bh, 2). slot = y*4+wid in 0..7; slot<7 -> tiles {slot, 13-slot},
// slot==7 -> {14}: every wave runs exactly 15 kt-iterations (load-balanced).
__global__ __launch_bounds__(256)
void flash_attn(const ushort_t* __restrict__ qb, const ushort_t* __restrict__ kb,
                const ushort_t* __restrict__ vtil, const float* __restrict__ rbt,
                ushort_t* __restrict__ ctxb, float* __restrict__ cst,
                uint4* __restrict__ pscr) {
  const int bh = blockIdx.x;
  const int b = bh >> 3, h = bh & 7;
  const int tid = threadIdx.x;
  const int wid = tid >> 6, lane = tid & 63;
  const int lm = lane & 15, quad = lane >> 4;

  __shared__ __align__(16) ushort_t sP[4][32 * PSTR];

  const int slot = blockIdx.y * 4 + wid;  // 0..7
  const int tA = (slot == 7) ? 14 : slot;
  const int tB = (slot == 7) ? -1 : 13 - slot;

  const ushort_t* qh = qb + (size_t)bh * NS * NDK;
  const ushort_t* kh = kb + (size_t)bh * NS * NDK;
  const ushort_t* vb = vtil + (size_t)bh * 15 * 2048;
  const float* rb = rbt + (size_t)h * 15 * NS * 32;

#pragma unroll 1
  for (int ti = 0; ti < 2; ++ti) {
    const int t = (ti == 0) ? tA : tB;
    if (t < 0) break;
    const int nkt = t + 1;
    uint4* pp = pscr + ((size_t)(bh * 120 + (t * (t + 1)) / 2)) * 128 + lane;

    short8 aq[2][2];
#pragma unroll
    for (int g = 0; g < 2; ++g) {
      aq[g][0] = *(const short8*)&qh[(t * 32 + g * 16 + lm) * NDK + quad * 8];
      aq[g][1] = *(const short8*)&qh[(t * 32 + g * 16 + lm) * NDK + 32 + quad * 8];
    }

    float lsum[2][4];
    floatx4 O[2][4];
    floatx4 zero4 = {0.f, 0.f, 0.f, 0.f};
#pragma unroll
    for (int g = 0; g < 2; ++g) {
#pragma unroll
      for (int r = 0; r < 4; ++r) lsum[g][r] = 0.f;
#pragma unroll
      for (int jd = 0; jd < 4; ++jd) O[g][jd] = zero4;
    }

    for (int kt = 0; kt < nkt; ++kt) {
      const int kvA = kt * 32 + lm;
      const int kvB = kvA + 16;
      short8 bkA0 = *(const short8*)&kh[kvA * NDK + quad * 8];
      short8 bkA1 = *(const short8*)&kh[kvA * NDK + 32 + quad * 8];
      short8 bkB0 = *(const short8*)&kh[kvB * NDK + quad * 8];
      short8 bkB1 = *(const short8*)&kh[kvB * NDK + 32 + quad * 8];
      short8 bv2[4];
#pragma unroll
      for (int jd = 0; jd < 4; ++jd)
        bv2[jd] = *(const short8*)&vb[kt * 2048 + (jd * 16 + lm) * 32 + quad * 8];
      float2 bb[2][4];
#pragma unroll
      for (int g = 0; g < 2; ++g)
#pragma unroll
        for (int r = 0; r < 4; ++r) {
          int i = t * 32 + g * 16 + quad * 4 + r;
          bb[g][r] = *(const float2*)&rb[((size_t)kt * NS + i) * 32 + 2 * lm];
        }

      floatx4 sA[2], sB[2];
      __builtin_amdgcn_s_setprio(1);
#pragma unroll
      for (int g = 0; g < 2; ++g) {
        floatx4 s = zero4;
        s = __builtin_amdgcn_mfma_f32_16x16x32_bf16(aq[g][0], bkA0, s, 0, 0, 0);
        s = __builtin_amdgcn_mfma_f32_16x16x32_bf16(aq[g][1], bkA1, s, 0, 0, 0);
        sA[g] = s;
        s = zero4;
        s = __builtin_amdgcn_mfma_f32_16x16x32_bf16(aq[g][0], bkB0, s, 0, 0, 0);
        s = __builtin_amdgcn_mfma_f32_16x16x32_bf16(aq[g][1], bkB1, s, 0, 0, 0);
        sB[g] = s;
      }
      __builtin_amdgcn_s_setprio(0);

      const bool diag = (kt == t);  // wave-uniform
#pragma unroll
      for (int g = 0; g < 2; ++g) {
        unsigned pw[4];
#pragma unroll
        for (int r = 0; r < 4; ++r) {
          float p0 = __builtin_amdgcn_exp2f(fmaf(sA[g][r], SCL, bb[g][r].x));
          float p1 = __builtin_amdgcn_exp2f(fmaf(sB[g][r], SCL, bb[g][r].y));
          if (diag) {
            int i = t * 32 + g * 16 + quad * 4 + r;
            if (kvA > i) p0 = 0.f;
            if (kvB > i) p1 = 0.f;
          }
          lsum[g][r] += p0 + p1;
          unsigned pk;
          asm("v_cvt_pk_bf16_f32 %0, %1, %2" : "=v"(pk) : "v"(p0), "v"(p1));
          sP[wid][(g * 16 + quad * 4 + r) * PSTR + lm] = (ushort_t)(pk & 0xffffu);
          sP[wid][(g * 16 + quad * 4 + r) * PSTR + 16 + lm] = (ushort_t)(pk >> 16);
          half2v hp = __builtin_amdgcn_cvt_pkrtz(p0, p1);
          pw[r] = *(unsigned*)&hp;
        }
        uint4 pq = {pw[0], pw[1], pw[2], pw[3]};
        pp[(size_t)kt * 128 + g * 64] = pq;  // fire-and-forget, 1KB/instr
      }

      __builtin_amdgcn_s_setprio(1);
#pragma unroll
      for (int g = 0; g < 2; ++g) {
        short8 ap = *(const short8*)&sP[wid][(g * 16 + lm) * PSTR + quad * 8];
#pragma unroll
        for (int jd = 0; jd < 4; ++jd)
          O[g][jd] = __builtin_amdgcn_mfma_f32_16x16x32_bf16(ap, bv2[jd], O[g][jd], 0, 0, 0);
      }
      __builtin_amdgcn_s_setprio(0);
    }

#pragma unroll
    for (int off = 1; off < 16; off <<= 1)
#pragma unroll
      for (int g = 0; g < 2; ++g)
#pragma unroll
        for (int r = 0; r < 4; ++r) lsum[g][r] += __shfl_xor(lsum[g][r], off, 64);

#pragma unroll
    for (int g = 0; g < 2; ++g) {
      float rinv[4];
#pragma unroll
      for (int r = 0; r < 4; ++r) rinv[r] = 1.f / lsum[g][r];
#pragma unroll
      for (int jd = 0; jd < 4; ++jd)
#pragma unroll
        for (int r = 0; r < 4; ++r) {
          int i = t * 32 + g * 16 + quad * 4 + r;
          ctxb[((size_t)b * NS + i) * ND + h * NDK + jd * 16 + lm] =
              f2bf(O[g][jd][r] * rinv[r]);
        }
      if (lm == 0) {
#pragma unroll
        for (int r = 0; r < 4; ++r) {
          int i = t * 32 + g * 16 + quad * 4 + r;
          cst[(size_t)bh * NS + i] = rinv[r];
        }
      }
    }
  }
}

// ---------------------------------------------------------------- attn_mean_p
__global__ __launch_bounds__(64)
void attn_mean_p(const uint4* __restrict__ pscr, const float* __restrict__ cst,
                 float* __restrict__ am) {
  const int b = blockIdx.x, t = blockIdx.y, kt = blockIdx.z;
  const int lane = threadIdx.x;
  const int lm = lane & 15, quad = lane >> 4;
  float* outp = am + ((size_t)b * NS + t * 32) * NS + (size_t)kt * 32;
  if (kt > t) {
#pragma unroll
    for (int g = 0; g < 2; ++g)
#pragma unroll
      for (int r = 0; r < 4; ++r) {
        int row = g * 16 + quad * 4 + r;
        outp[(size_t)row * NS + lm] = 0.f;
        outp[(size_t)row * NS + 16 + lm] = 0.f;
      }
    return;
  }
  const int m = (t * (t + 1)) / 2 + kt;
  float a0[2][4], a1[2][4];
#pragma unroll
  for (int g = 0; g < 2; ++g)
#pragma unroll
    for (int r = 0; r < 4; ++r) { a0[g][r] = 0.f; a1[g][r] = 0.f; }

#pragma unroll
  for (int h = 0; h < NH; ++h) {
    const uint4* pp = pscr + ((size_t)(b * NH + h) * 120 + m) * 128 + lane;
    uint4 q0 = pp[0];        // g=0: rows quad*4..+3 of 0..15, cols lm/16+lm
    uint4 q1 = pp[64];       // g=1
    unsigned pu[8] = {q0.x, q0.y, q0.z, q0.w, q1.x, q1.y, q1.z, q1.w};
    const float* cp = cst + (size_t)(b * NH + h) * NS + t * 32 + quad * 4;
    float4 rv0 = *(const float4*)cp;
    float4 rv1 = *(const float4*)(cp + 16);
    float rv[8] = {rv0.x, rv0.y, rv0.z, rv0.w, rv1.x, rv1.y, rv1.z, rv1.w};
#pragma unroll
    for (int g = 0; g < 2; ++g)
#pragma unroll
      for (int r = 0; r < 4; ++r) {
        half2v hp = *(half2v*)&pu[g * 4 + r];
        a0[g][r] = fmaf((float)hp.x, rv[g * 4 + r], a0[g][r]);
        a1[g][r] = fmaf((float)hp.y, rv[g * 4 + r], a1[g][r]);
      }
  }

#pragma unroll
  for (int g = 0; g < 2; ++g)
#pragma unroll
    for (int r = 0; r < 4; ++r) {
      int row = g * 16 + quad * 4 + r;
      outp[(size_t)row * NS + lm] = a0[g][r] * 0.125f;
      outp[(size_t)row * NS + 16 + lm] = a1[g][r] * 0.125f;
    }
}

// ---------------------------------------------------------------- out_gemm
// ctx @ woT + bo, 2-phase double-buffered LDS staging (128x128, BK=64).
__global__ __launch_bounds__(256)
void out_gemm(const ushort_t* __restrict__ ctxb, const ushort_t* __restrict__ woT,
              const float* __restrict__ bo, float* __restrict__ out) {
  __shared__ __align__(16) ushort_t sA[2][128 * 64];
  __shared__ __align__(16) ushort_t sB[2][128 * 64];
  const int tid = threadIdx.x;
  const int wid = tid >> 6, lane = tid & 63;
  const int lm = lane & 15, quad = lane >> 4;
  const int wr = wid >> 1, wc = wid & 1;
  const int row0 = blockIdx.x * 128;
  const int col0 = blockIdx.y * 128;
  const int srow_ = tid >> 3, skc = tid & 7;
  const int skcs = skc ^ (srow_ & 7);

  floatx4 zero4 = {0.f, 0.f, 0.f, 0.f};
  floatx4 acc[4][4];
#pragma unroll
  for (int i = 0; i < 4; ++i)
#pragma unroll
    for (int j = 0; j < 4; ++j) acc[i][j] = zero4;

#pragma unroll
  for (int c = 0; c < 4; ++c) {
    int row = c * 32 + srow_;
    GLOAD_LDS16(ctxb + (row0 + row) * ND + skcs * 8, &sA[0][(c * 256 + wid * 64) * 8]);
    GLOAD_LDS16(woT + (col0 + row) * ND + skcs * 8, &sB[0][(c * 256 + wid * 64) * 8]);
  }
  __syncthreads();

  int buf = 0;
  for (int t = 0; t < 8; ++t) {
    if (t < 7) {
      int k0n = (t + 1) * 64;
#pragma unroll
      for (int c = 0; c < 4; ++c) {
        int row = c * 32 + srow_;
        GLOAD_LDS16(ctxb + (row0 + row) * ND + k0n + skcs * 8,
                    &sA[buf ^ 1][(c * 256 + wid * 64) * 8]);
        GLOAD_LDS16(woT + (col0 + row) * ND + k0n + skcs * 8,
                    &sB[buf ^ 1][(c * 256 + wid * 64) * 8]);
      }
    }
#pragma unroll
    for (int h2 = 0; h2 < 2; ++h2) {
      short8 a[4], b[4];
#pragma unroll
      for (int i = 0; i < 4; ++i) {
        int row = wr * 64 + i * 16 + lm;
        a[i] = *(const short8*)&sA[buf][row * 64 + (((h2 << 2) | quad) ^ (lm & 7)) * 8];
      }
#pragma unroll
      for (int j = 0; j < 4; ++j) {
        int row = wc * 64 + j * 16 + lm;
        b[j] = *(const short8*)&sB[buf][row * 64 + (((h2 << 2) | quad) ^ (lm & 7)) * 8];
      }
#pragma unroll
      for (int i = 0; i < 4; ++i)
#pragma unroll
        for (int j = 0; j < 4; ++j)
          acc[i][j] = __builtin_amdgcn_mfma_f32_16x16x32_bf16(a[i], b[j], acc[i][j], 0, 0, 0);
    }
    __syncthreads();
    buf ^= 1;
  }

  float bsv[4];
#pragma unroll
  for (int j = 0; j < 4; ++j) bsv[j] = bo[col0 + wc * 64 + j * 16 + lm];

#pragma unroll
  for (int i = 0; i < 4; ++i)
#pragma unroll
    for (int j = 0; j < 4; ++j)
#pragma unroll
      for (int r = 0; r < 4; ++r) {
        int m = row0 + wr * 64 + i * 16 + quad * 4 + r;
        int n = col0 + wc * 64 + j * 16 + lm;
        out[m * ND + n] = acc[i][j][r] + bsv[j];
      }
}

// ---------------------------------------------------------------- launch
extern "C" void kernel_launch(void* const* d_in, const int* in_sizes, int n_in,
                              void* d_out, int out_size, void* d_ws, size_t ws_size,
                              hipStream_t stream) {
  const float* x  = (const float*)d_in[0];
  const float* wq = (const float*)d_in[1];
  const float* bq = (const float*)d_in[2];
  const float* wk = (const float*)d_in[3];
  const float* bk = (const float*)d_in[4];
  const float* wv = (const float*)d_in[5];
  const float* bv = (const float*)d_in[6];
  const float* wo = (const float*)d_in[7];
  const float* bo = (const float*)d_in[8];
  const float* rel_bias = (const float*)d_in[9];

  char* w = (char*)d_ws;
  ushort_t* xb  = (ushort_t*)w;                       // 15,728,640 B
  ushort_t* wqT = (ushort_t*)(w + 15728640);          // 4 x 524,288 B
  ushort_t* wkT = wqT + 262144;
  ushort_t* wvT = wkT + 262144;
  ushort_t* woT = wvT + 262144;
  ushort_t* qb  = (ushort_t*)(w + 15728640 + 4 * 524288);
  ushort_t* kb  = qb + 7864320;
  ushort_t* vtil = kb + 7864320;                      // tiled V
  ushort_t* ctxb = vtil + 7864320;
  float* cstat = (float*)(w + 80740352);              // rinv [bh][i], 491,520 B
  uint4* pscr = (uint4*)(w + 81264640);               // P scratch, 62,914,560 B
  // rbt (14,745,600 B) aliases xb — xb is dead after qkv_gemm
  float* rbt = (float*)w;

  float* out0 = (float*)d_out;        // [32,480,512]
  float* attn_mean = out0 + 7864320;  // [32,480,480]

  cvt_xw<<<dim3(8704), dim3(256), 0, stream>>>(x, wq, wk, wv, wo, xb, wqT, wkT, wvT, woT);
  qkv_gemm<<<dim3(128, 4, 3), dim3(256), 0, stream>>>(xb, wqT, wkT, wvT, bq, bk, bv,
                                                      qb, kb, vtil);
  cvt_rbt<<<dim3(15, 30, 8), dim3(256), 0, stream>>>(rel_bias, rbt);
  flash_attn<<<dim3(256, 2), dim3(256), 0, stream>>>(qb, kb, vtil, rbt, ctxb, cstat, pscr);
  attn_mean_p<<<dim3(32, 15, 15), dim3(64), 0, stream>>>(pscr, cstat, attn_mean);
  out_gemm<<<dim3(120, 4), dim3(256), 0, stream>>>(ctxb, woT, bo, out0);
}

// Round 13
// 226.948 us; speedup vs baseline: 1.0252x; 1.0194x over previous
//
#include <hip/hip_runtime.h>
#include <hip/hip_bf16.h>

// B=32, S=480, D=512, H=8, dk=64. Outputs: out[32,480,512] fp32,
// attn_mean[32,480,480] fp32, concatenated in d_out.
//
// Pipeline (bf16 MFMA 16x16x32), 5 launches:
//  1. cvt_xw     : x fp32->bf16 (blocks <7680) + w* transpose (blocks >=7680)
//  2. qkv_gemm   : 128x128 BK=64 2-phase dbuf (proven best: BK32 -> +conflicts
//                  +barriers 60us; 64x128 -> FETCH+71% 65us; this: 48.9us).
//                  z<2 -> q/k gemm, z==2 -> V tiled gemm.
//  3. flash_attn : balanced pairing slot s<7 -> {s,13-s}, s==7 -> {14};
//                  bias read DIRECTLY from rel_bias (L2-resident, x log2e
//                  folded in) — cvt_rbt kernel deleted. P tiles fp16 -> pscr
//                  coalesced; cst = 1/lsum [bh][i].
//  4. attn_mean_p: streaming mean: read pscr (8 heads) * rinv -> fp32.
//  5. out_gemm   : ctx @ woT + bo -> fp32, 128x128 BK=64 2-phase dbuf.

typedef unsigned short ushort_t;
typedef __attribute__((ext_vector_type(8))) short short8;
typedef __attribute__((ext_vector_type(4))) float floatx4;
typedef __attribute__((ext_vector_type(2))) __fp16 half2v;

#define NB 32
#define NS 480
#define ND 512
#define NH 8
#define NDK 64
#define MAXLEN 500
#define PSTR 36   // sP row stride (ushorts): b128 frag reads <=2-way bank alias
#define SCL 0.18033688f   // 0.125 * log2(e)
#define L2E 1.44269504f   // log2(e)

__device__ __forceinline__ ushort_t f2bf(float f) {
  union { float f; unsigned u; } v; v.f = f;
  unsigned r = v.u + 0x7FFFu + ((v.u >> 16) & 1u);
  return (ushort_t)(r >> 16);
}

#define GLOAD_LDS16(g, l)                                                      \
  __builtin_amdgcn_global_load_lds(                                            \
      (const __attribute__((address_space(1))) void*)(g),                      \
      (__attribute__((address_space(3))) void*)(l), 16, 0, 0)

// ---------------------------------------------------------------- cvt_xw
// blocks [0,7680): x fp32->bf16 vectorized. blocks [7680,8704): w transpose.
__global__ __launch_bounds__(256)
void cvt_xw(const float* __restrict__ x, const float* __restrict__ wq,
            const float* __restrict__ wk, const float* __restrict__ wv,
            const float* __restrict__ wo, ushort_t* __restrict__ xb,
            ushort_t* __restrict__ wqT, ushort_t* __restrict__ wkT,
            ushort_t* __restrict__ wvT, ushort_t* __restrict__ woT) {
  __shared__ float t[32][33];
  const int bid = blockIdx.x;
  if (bid < 7680) {
    int idx = bid * 256 + threadIdx.x;
    float4 v = ((const float4*)x)[idx];
    ushort4 o;
    o.x = f2bf(v.x); o.y = f2bf(v.y); o.z = f2bf(v.z); o.w = f2bf(v.w);
    ((ushort4*)xb)[idx] = o;
    return;
  }
  const int q = bid - 7680;
  const int z = q >> 8;
  const float* w = (z == 0) ? wq : (z == 1) ? wk : (z == 2) ? wv : wo;
  ushort_t* wT = (z == 0) ? wqT : (z == 1) ? wkT : (z == 2) ? wvT : woT;
  int k0 = (q & 15) * 32, n0 = ((q >> 4) & 15) * 32;
  int tx = threadIdx.x & 31, ty = threadIdx.x >> 5;
#pragma unroll
  for (int yy = 0; yy < 4; ++yy)
    t[ty + yy * 8][tx] = w[(k0 + ty + yy * 8) * ND + n0 + tx];
  __syncthreads();
#pragma unroll
  for (int yy = 0; yy < 4; ++yy)
    wT[(n0 + ty + yy * 8) * ND + k0 + tx] = f2bf(t[tx][ty + yy * 8]);
}

// ---------------------------------------------------------------- qkv_gemm
// 128x128 BK=64 2-phase dbuf, 64KB LDS. z in {0,1}: q/k gemm (x<120).
// z == 2: V tiled gemm, b = x>>2, ddt = x&3.
__global__ __launch_bounds__(256)
void qkv_gemm(const ushort_t* __restrict__ xb,
              const ushort_t* __restrict__ wqT, const ushort_t* __restrict__ wkT,
              const ushort_t* __restrict__ wvT,
              const float* __restrict__ bq, const float* __restrict__ bk,
              const float* __restrict__ bv,
              ushort_t* __restrict__ qb, ushort_t* __restrict__ kb,
              ushort_t* __restrict__ vtil) {
  __shared__ __align__(16) ushort_t sA[2][128 * 64];
  __shared__ __align__(16) ushort_t sB[2][128 * 64];
  const int tid = threadIdx.x;
  const int wid = tid >> 6, lane = tid & 63;
  const int lm = lane & 15, quad = lane >> 4;
  const int wr = wid >> 1, wc = wid & 1;
  const int z = blockIdx.z;

  floatx4 zero4 = {0.f, 0.f, 0.f, 0.f};
  floatx4 acc[4][4];
#pragma unroll
  for (int i = 0; i < 4; ++i)
#pragma unroll
    for (int j = 0; j < 4; ++j) acc[i][j] = zero4;

  // staging geometry
  const int srow_ = tid >> 3, skc = tid & 7;
  const int skcs = skc ^ (srow_ & 7);

  if (z < 2) {
    if (blockIdx.x >= 120) return;
    const int row0 = blockIdx.x * 128;
    const int col0 = blockIdx.y * 128;
    const ushort_t* Bt = (z == 0) ? wqT : wkT;
    const float* bias = (z == 0) ? bq : bk;

    // prologue: stage k0=0 into buf 0
#pragma unroll
    for (int c = 0; c < 4; ++c) {
      int row = c * 32 + srow_;
      GLOAD_LDS16(xb + (row0 + row) * ND + skcs * 8, &sA[0][(c * 256 + wid * 64) * 8]);
      GLOAD_LDS16(Bt + (col0 + row) * ND + skcs * 8, &sB[0][(c * 256 + wid * 64) * 8]);
    }
    __syncthreads();

    int buf = 0;
    for (int t = 0; t < 8; ++t) {
      if (t < 7) {
        int k0n = (t + 1) * 64;
#pragma unroll
        for (int c = 0; c < 4; ++c) {
          int row = c * 32 + srow_;
          GLOAD_LDS16(xb + (row0 + row) * ND + k0n + skcs * 8,
                      &sA[buf ^ 1][(c * 256 + wid * 64) * 8]);
          GLOAD_LDS16(Bt + (col0 + row) * ND + k0n + skcs * 8,
                      &sB[buf ^ 1][(c * 256 + wid * 64) * 8]);
        }
      }
#pragma unroll
      for (int h2 = 0; h2 < 2; ++h2) {
        short8 a[4], b[4];
#pragma unroll
        for (int i = 0; i < 4; ++i) {
          int row = wr * 64 + i * 16 + lm;
          a[i] = *(const short8*)&sA[buf][row * 64 + (((h2 << 2) | quad) ^ (lm & 7)) * 8];
        }
#pragma unroll
        for (int j = 0; j < 4; ++j) {
          int row = wc * 64 + j * 16 + lm;
          b[j] = *(const short8*)&sB[buf][row * 64 + (((h2 << 2) | quad) ^ (lm & 7)) * 8];
        }
#pragma unroll
        for (int i = 0; i < 4; ++i)
#pragma unroll
          for (int j = 0; j < 4; ++j)
            acc[i][j] = __builtin_amdgcn_mfma_f32_16x16x32_bf16(a[i], b[j], acc[i][j], 0, 0, 0);
      }
      __syncthreads();
      buf ^= 1;
    }

    float bsv[4];
#pragma unroll
    for (int j = 0; j < 4; ++j) bsv[j] = bias[col0 + wc * 64 + j * 16 + lm];

#pragma unroll
    for (int i = 0; i < 4; ++i)
#pragma unroll
      for (int j = 0; j < 4; ++j)
#pragma unroll
        for (int r = 0; r < 4; ++r) {
          int m = row0 + wr * 64 + i * 16 + quad * 4 + r;
          int n = col0 + wc * 64 + j * 16 + lm;
          float val = acc[i][j][r] + bsv[j];
          int bb = m / NS, s = m - bb * NS;
          int h = n >> 6, d = n & 63;
          ushort_t o = f2bf(val);
          if (z == 0) qb[((bb * NH + h) * NS + s) * NDK + d] = o;
          else        kb[((bb * NH + h) * NS + s) * NDK + d] = o;
        }
  } else {
    const int b = blockIdx.x >> 2;
    const int row0 = (blockIdx.x & 3) * 128;  // dd
    const int col0 = blockIdx.y * 128;        // s
    const ushort_t* xbb = xb + (size_t)b * NS * ND;

#pragma unroll
    for (int c = 0; c < 4; ++c) {
      int row = c * 32 + srow_;
      GLOAD_LDS16(wvT + (row0 + row) * ND + skcs * 8, &sA[0][(c * 256 + wid * 64) * 8]);
      int sr = min(col0 + row, NS - 1);
      GLOAD_LDS16(xbb + sr * ND + skcs * 8, &sB[0][(c * 256 + wid * 64) * 8]);
    }
    __syncthreads();

    int buf = 0;
    for (int t = 0; t < 8; ++t) {
      if (t < 7) {
        int k0n = (t + 1) * 64;
#pragma unroll
        for (int c = 0; c < 4; ++c) {
          int row = c * 32 + srow_;
          GLOAD_LDS16(wvT + (row0 + row) * ND + k0n + skcs * 8,
                      &sA[buf ^ 1][(c * 256 + wid * 64) * 8]);
          int sr = min(col0 + row, NS - 1);
          GLOAD_LDS16(xbb + sr * ND + k0n + skcs * 8,
                      &sB[buf ^ 1][(c * 256 + wid * 64) * 8]);
        }
      }
#pragma unroll
      for (int h2 = 0; h2 < 2; ++h2) {
        short8 a[4], b2[4];
#pragma unroll
        for (int i = 0; i < 4; ++i) {
          int row = wr * 64 + i * 16 + lm;
          a[i] = *(const short8*)&sA[buf][row * 64 + (((h2 << 2) | quad) ^ (lm & 7)) * 8];
        }
#pragma unroll
        for (int j = 0; j < 4; ++j) {
          int row = wc * 64 + j * 16 + lm;
          b2[j] = *(const short8*)&sB[buf][row * 64 + (((h2 << 2) | quad) ^ (lm & 7)) * 8];
        }
#pragma unroll
        for (int i = 0; i < 4; ++i)
#pragma unroll
          for (int j = 0; j < 4; ++j)
            acc[i][j] = __builtin_amdgcn_mfma_f32_16x16x32_bf16(a[i], b2[j], acc[i][j], 0, 0, 0);
      }
      __syncthreads();
      buf ^= 1;
    }

#pragma unroll
    for (int i = 0; i < 4; ++i)
#pragma unroll
      for (int r = 0; r < 4; ++r) {
        int m = row0 + wr * 64 + i * 16 + quad * 4 + r;  // dd = h*64 + d
        float bias = bv[m];
#pragma unroll
        for (int j = 0; j < 4; ++j) {
          int n = col0 + wc * 64 + j * 16 + lm;  // s
          if (n < NS) {
            size_t idx = (((size_t)b * NH + (m >> 6)) * 15 + (n >> 5)) * 2048 +
                         (m & 63) * 32 + (n & 31);
            vtil[idx] = f2bf(acc[i][j][r] + bias);
          }
        }
      }
  }
}

// ---------------------------------------------------------------- flash_attn
// grid (256 bh, 2). slot = y*4+wid in 0..7; slot<7 -> tiles {slot, 13-slot},
// slot==7 -> {14}. Bias read directly from rel_bias (L2-resident), log2e
// applied in-register. P tiles fp16 -> pscr coalesced. cst = 1/lsum [bh][i].
__global__ __launch_bounds__(256)
void flash_attn(const ushort_t* __restrict__ qb, const ushort_t* __restrict__ kb,
                const ushort_t* __restrict__ vtil, const float* __restrict__ relb,
                ushort_t* __restrict__ ctxb, float* __restrict__ cst,
                uint4* __restrict__ pscr) {
  const int bh = blockIdx.x;
  const int b = bh >> 3, h = bh & 7;
  const int tid = threadIdx.x;
  const int wid = tid >> 6, lane = tid & 63;
  const int lm = lane & 15, quad = lane >> 4;

  __shared__ __align__(16) ushort_t sP[4][32 * PSTR];

  const int slot = blockIdx.y * 4 + wid;  // 0..7
  const int tA = (slot == 7) ? 14 : slot;
  const int tB = (slot == 7) ? -1 : 13 - slot;

  const ushort_t* qh = qb + (size_t)bh * NS * NDK;
  const ushort_t* kh = kb + (size_t)bh * NS * NDK;
  const ushort_t* vb = vtil + (size_t)bh * 15 * 2048;
  const float* rb = relb + (size_t)h * MAXLEN * MAXLEN;

#pragma unroll 1
  for (int ti = 0; ti < 2; ++ti) {
    const int t = (ti == 0) ? tA : tB;
    if (t < 0) break;
    const int nkt = t + 1;
    uint4* pp = pscr + ((size_t)(bh * 120 + (t * (t + 1)) / 2)) * 128 + lane;

    short8 aq[2][2];
#pragma unroll
    for (int g = 0; g < 2; ++g) {
      aq[g][0] = *(const short8*)&qh[(t * 32 + g * 16 + lm) * NDK + quad * 8];
      aq[g][1] = *(const short8*)&qh[(t * 32 + g * 16 + lm) * NDK + 32 + quad * 8];
    }

    float lsum[2][4];
    floatx4 O[2][4];
    floatx4 zero4 = {0.f, 0.f, 0.f, 0.f};
#pragma unroll
    for (int g = 0; g < 2; ++g) {
#pragma unroll
      for (int r = 0; r < 4; ++r) lsum[g][r] = 0.f;
#pragma unroll
      for (int jd = 0; jd < 4; ++jd) O[g][jd] = zero4;
    }

    for (int kt = 0; kt < nkt; ++kt) {
      const int kvA = kt * 32 + lm;
      const int kvB = kvA + 16;
      short8 bkA0 = *(const short8*)&kh[kvA * NDK + quad * 8];
      short8 bkA1 = *(const short8*)&kh[kvA * NDK + 32 + quad * 8];
      short8 bkB0 = *(const short8*)&kh[kvB * NDK + quad * 8];
      short8 bkB1 = *(const short8*)&kh[kvB * NDK + 32 + quad * 8];
      short8 bv2[4];
#pragma unroll
      for (int jd = 0; jd < 4; ++jd)
        bv2[jd] = *(const short8*)&vb[kt * 2048 + (jd * 16 + lm) * 32 + quad * 8];
      float2 bb[2][4];
#pragma unroll
      for (int g = 0; g < 2; ++g)
#pragma unroll
        for (int r = 0; r < 4; ++r) {
          int i = t * 32 + g * 16 + quad * 4 + r;
          const float* bp = &rb[(size_t)i * MAXLEN + kt * 32 + lm];
          bb[g][r].x = bp[0] * L2E;
          bb[g][r].y = bp[16] * L2E;
        }

      floatx4 sA[2], sB[2];
      __builtin_amdgcn_s_setprio(1);
#pragma unroll
      for (int g = 0; g < 2; ++g) {
        floatx4 s = zero4;
        s = __builtin_amdgcn_mfma_f32_16x16x32_bf16(aq[g][0], bkA0, s, 0, 0, 0);
        s = __builtin_amdgcn_mfma_f32_16x16x32_bf16(aq[g][1], bkA1, s, 0, 0, 0);
        sA[g] = s;
        s = zero4;
        s = __builtin_amdgcn_mfma_f32_16x16x32_bf16(aq[g][0], bkB0, s, 0, 0, 0);
        s = __builtin_amdgcn_mfma_f32_16x16x32_bf16(aq[g][1], bkB1, s, 0, 0, 0);
        sB[g] = s;
      }
      __builtin_amdgcn_s_setprio(0);

      const bool diag = (kt == t);  // wave-uniform
#pragma unroll
      for (int g = 0; g < 2; ++g) {
        unsigned pw[4];
#pragma unroll
        for (int r = 0; r < 4; ++r) {
          float p0 = __builtin_amdgcn_exp2f(fmaf(sA[g][r], SCL, bb[g][r].x));
          float p1 = __builtin_amdgcn_exp2f(fmaf(sB[g][r], SCL, bb[g][r].y));
          if (diag) {
            int i = t * 32 + g * 16 + quad * 4 + r;
            if (kvA > i) p0 = 0.f;
            if (kvB > i) p1 = 0.f;
          }
          lsum[g][r] += p0 + p1;
          unsigned pk;
          asm("v_cvt_pk_bf16_f32 %0, %1, %2" : "=v"(pk) : "v"(p0), "v"(p1));
          sP[wid][(g * 16 + quad * 4 + r) * PSTR + lm] = (ushort_t)(pk & 0xffffu);
          sP[wid][(g * 16 + quad * 4 + r) * PSTR + 16 + lm] = (ushort_t)(pk >> 16);
          half2v hp = __builtin_amdgcn_cvt_pkrtz(p0, p1);
          pw[r] = *(unsigned*)&hp;
        }
        uint4 pq = {pw[0], pw[1], pw[2], pw[3]};
        pp[(size_t)kt * 128 + g * 64] = pq;  // fire-and-forget, 1KB/instr
      }

      __builtin_amdgcn_s_setprio(1);
#pragma unroll
      for (int g = 0; g < 2; ++g) {
        short8 ap = *(const short8*)&sP[wid][(g * 16 + lm) * PSTR + quad * 8];
#pragma unroll
        for (int jd = 0; jd < 4; ++jd)
          O[g][jd] = __builtin_amdgcn_mfma_f32_16x16x32_bf16(ap, bv2[jd], O[g][jd], 0, 0, 0);
      }
      __builtin_amdgcn_s_setprio(0);
    }

#pragma unroll
    for (int off = 1; off < 16; off <<= 1)
#pragma unroll
      for (int g = 0; g < 2; ++g)
#pragma unroll
        for (int r = 0; r < 4; ++r) lsum[g][r] += __shfl_xor(lsum[g][r], off, 64);

#pragma unroll
    for (int g = 0; g < 2; ++g) {
      float rinv[4];
#pragma unroll
      for (int r = 0; r < 4; ++r) rinv[r] = 1.f / lsum[g][r];
#pragma unroll
      for (int jd = 0; jd < 4; ++jd)
#pragma unroll
        for (int r = 0; r < 4; ++r) {
          int i = t * 32 + g * 16 + quad * 4 + r;
          ctxb[((size_t)b * NS + i) * ND + h * NDK + jd * 16 + lm] =
              f2bf(O[g][jd][r] * rinv[r]);
        }
      if (lm == 0) {
#pragma unroll
        for (int r = 0; r < 4; ++r) {
          int i = t * 32 + g * 16 + quad * 4 + r;
          cst[(size_t)bh * NS + i] = rinv[r];
        }
      }
    }
  }
}

// ---------------------------------------------------------------- attn_mean_p
__global__ __launch_bounds__(64)
void attn_mean_p(const uint4* __restrict__ pscr, const float* __restrict__ cst,
                 float* __restrict__ am) {
  const int b = blockIdx.x, t = blockIdx.y, kt = blockIdx.z;
  const int lane = threadIdx.x;
  const int lm = lane & 15, quad = lane >> 4;
  float* outp = am + ((size_t)b * NS + t * 32) * NS + (size_t)kt * 32;
  if (kt > t) {
#pragma unroll
    for (int g = 0; g < 2; ++g)
#pragma unroll
      for (int r = 0; r < 4; ++r) {
        int row = g * 16 + quad * 4 + r;
        outp[(size_t)row * NS + lm] = 0.f;
        outp[(size_t)row * NS + 16 + lm] = 0.f;
      }
    return;
  }
  const int m = (t * (t + 1)) / 2 + kt;
  float a0[2][4], a1[2][4];
#pragma unroll
  for (int g = 0; g < 2; ++g)
#pragma unroll
    for (int r = 0; r < 4; ++r) { a0[g][r] = 0.f; a1[g][r] = 0.f; }

#pragma unroll
  for (int h = 0; h < NH; ++h) {
    const uint4* pp = pscr + ((size_t)(b * NH + h) * 120 + m) * 128 + lane;
    uint4 q0 = pp[0];        // g=0: rows quad*4..+3 of 0..15, cols lm/16+lm
    uint4 q1 = pp[64];       // g=1
    unsigned pu[8] = {q0.x, q0.y, q0.z, q0.w, q1.x, q1.y, q1.z, q1.w};
    const float* cp = cst + (size_t)(b * NH + h) * NS + t * 32 + quad * 4;
    float4 rv0 = *(const float4*)cp;
    float4 rv1 = *(const float4*)(cp + 16);
    float rv[8] = {rv0.x, rv0.y, rv0.z, rv0.w, rv1.x, rv1.y, rv1.z, rv1.w};
#pragma unroll
    for (int g = 0; g < 2; ++g)
#pragma unroll
      for (int r = 0; r < 4; ++r) {
        half2v hp = *(half2v*)&pu[g * 4 + r];
        a0[g][r] = fmaf((float)hp.x, rv[g * 4 + r], a0[g][r]);
        a1[g][r] = fmaf((float)hp.y, rv[g * 4 + r], a1[g][r]);
      }
  }

#pragma unroll
  for (int g = 0; g < 2; ++g)
#pragma unroll
    for (int r = 0; r < 4; ++r) {
      int row = g * 16 + quad * 4 + r;
      outp[(size_t)row * NS + lm] = a0[g][r] * 0.125f;
      outp[(size_t)row * NS + 16 + lm] = a1[g][r] * 0.125f;
    }
}

// ---------------------------------------------------------------- out_gemm
// ctx @ woT + bo, 2-phase double-buffered LDS staging (128x128, BK=64).
__global__ __launch_bounds__(256)
void out_gemm(const ushort_t* __restrict__ ctxb, const ushort_t* __restrict__ woT,
              const float* __restrict__ bo, float* __restrict__ out) {
  __shared__ __align__(16) ushort_t sA[2][128 * 64];
  __shared__ __align__(16) ushort_t sB[2][128 * 64];
  const int tid = threadIdx.x;
  const int wid = tid >> 6, lane = tid & 63;
  const int lm = lane & 15, quad = lane >> 4;
  const int wr = wid >> 1, wc = wid & 1;
  const int row0 = blockIdx.x * 128;
  const int col0 = blockIdx.y * 128;
  const int srow_ = tid >> 3, skc = tid & 7;
  const int skcs = skc ^ (srow_ & 7);

  floatx4 zero4 = {0.f, 0.f, 0.f, 0.f};
  floatx4 acc[4][4];
#pragma unroll
  for (int i = 0; i < 4; ++i)
#pragma unroll
    for (int j = 0; j < 4; ++j) acc[i][j] = zero4;

#pragma unroll
  for (int c = 0; c < 4; ++c) {
    int row = c * 32 + srow_;
    GLOAD_LDS16(ctxb + (row0 + row) * ND + skcs * 8, &sA[0][(c * 256 + wid * 64) * 8]);
    GLOAD_LDS16(woT + (col0 + row) * ND + skcs * 8, &sB[0][(c * 256 + wid * 64) * 8]);
  }
  __syncthreads();

  int buf = 0;
  for (int t = 0; t < 8; ++t) {
    if (t < 7) {
      int k0n = (t + 1) * 64;
#pragma unroll
      for (int c = 0; c < 4; ++c) {
        int row = c * 32 + srow_;
        GLOAD_LDS16(ctxb + (row0 + row) * ND + k0n + skcs * 8,
                    &sA[buf ^ 1][(c * 256 + wid * 64) * 8]);
        GLOAD_LDS16(woT + (col0 + row) * ND + k0n + skcs * 8,
                    &sB[buf ^ 1][(c * 256 + wid * 64) * 8]);
      }
    }
#pragma unroll
    for (int h2 = 0; h2 < 2; ++h2) {
      short8 a[4], b[4];
#pragma unroll
      for (int i = 0; i < 4; ++i) {
        int row = wr * 64 + i * 16 + lm;
        a[i] = *(const short8*)&sA[buf][row * 64 + (((h2 << 2) | quad) ^ (lm & 7)) * 8];
      }
#pragma unroll
      for (int j = 0; j < 4; ++j) {
        int row = wc * 64 + j * 16 + lm;
        b[j] = *(const short8*)&sB[buf][row * 64 + (((h2 << 2) | quad) ^ (lm & 7)) * 8];
      }
#pragma unroll
      for (int i = 0; i < 4; ++i)
#pragma unroll
        for (int j = 0; j < 4; ++j)
          acc[i][j] = __builtin_amdgcn_mfma_f32_16x16x32_bf16(a[i], b[j], acc[i][j], 0, 0, 0);
    }
    __syncthreads();
    buf ^= 1;
  }

  float bsv[4];
#pragma unroll
  for (int j = 0; j < 4; ++j) bsv[j] = bo[col0 + wc * 64 + j * 16 + lm];

#pragma unroll
  for (int i = 0; i < 4; ++i)
#pragma unroll
    for (int j = 0; j < 4; ++j)
#pragma unroll
      for (int r = 0; r < 4; ++r) {
        int m = row0 + wr * 64 + i * 16 + quad * 4 + r;
        int n = col0 + wc * 64 + j * 16 + lm;
        out[m * ND + n] = acc[i][j][r] + bsv[j];
      }
}

// ---------------------------------------------------------------- launch
extern "C" void kernel_launch(void* const* d_in, const int* in_sizes, int n_in,
                              void* d_out, int out_size, void* d_ws, size_t ws_size,
                              hipStream_t stream) {
  const float* x  = (const float*)d_in[0];
  const float* wq = (const float*)d_in[1];
  const float* bq = (const float*)d_in[2];
  const float* wk = (const float*)d_in[3];
  const float* bk = (const float*)d_in[4];
  const float* wv = (const float*)d_in[5];
  const float* bv = (const float*)d_in[6];
  const float* wo = (const float*)d_in[7];
  const float* bo = (const float*)d_in[8];
  const float* rel_bias = (const float*)d_in[9];

  char* w = (char*)d_ws;
  ushort_t* xb  = (ushort_t*)w;                       // 15,728,640 B
  ushort_t* wqT = (ushort_t*)(w + 15728640);          // 4 x 524,288 B
  ushort_t* wkT = wqT + 262144;
  ushort_t* wvT = wkT + 262144;
  ushort_t* woT = wvT + 262144;
  ushort_t* qb  = (ushort_t*)(w + 15728640 + 4 * 524288);
  ushort_t* kb  = qb + 7864320;
  ushort_t* vtil = kb + 7864320;                      // tiled V
  ushort_t* ctxb = vtil + 7864320;
  float* cstat = (float*)(w + 80740352);              // rinv [bh][i], 491,520 B
  uint4* pscr = (uint4*)(w + 81264640);               // P scratch, 62,914,560 B

  float* out0 = (float*)d_out;        // [32,480,512]
  float* attn_mean = out0 + 7864320;  // [32,480,480]

  cvt_xw<<<dim3(8704), dim3(256), 0, stream>>>(x, wq, wk, wv, wo, xb, wqT, wkT, wvT, woT);
  qkv_gemm<<<dim3(128, 4, 3), dim3(256), 0, stream>>>(xb, wqT, wkT, wvT, bq, bk, bv,
                                                      qb, kb, vtil);
  flash_attn<<<dim3(256, 2), dim3(256), 0, stream>>>(qb, kb, vtil, rel_bias, ctxb,
                                                     cstat, pscr);
  attn_mean_p<<<dim3(32, 15, 15), dim3(64), 0, stream>>>(pscr, cstat, attn_mean);
  out_gemm<<<dim3(120, 4), dim3(256), 0, stream>>>(ctxb, woT, bo, out0);
}

// Round 14
// 220.859 us; speedup vs baseline: 1.0534x; 1.0276x over previous
//
#include <hip/hip_runtime.h>
#include <hip/hip_bf16.h>

// B=32, S=480, D=512, H=8, dk=64. Outputs: out[32,480,512] fp32,
// attn_mean[32,480,480] fp32, concatenated in d_out.
//
// Pipeline (bf16 MFMA 16x16x32), 6 launches — BEST-KNOWN CONFIG (round 10,
// 220.9us). Rounds 11-13 all regressed: 64x128 tile -> FETCH +71%; BK=32 ->
// bank conflicts + 2x barriers; deleting cvt_rbt -> flash +7us (16 scalar
// bias loads vs 8 float2, VGPR 88->108).
//  1. cvt_xw     : x fp32->bf16 (blocks <7680) + w* transpose (blocks >=7680)
//  2. qkv_gemm   : 128x128 BK=64 2-phase dbuf LDS (stage t+1 before compute t).
//  3. cvt_rbt    : rel_bias*log2e -> paired rbt (MUST follow qkv: aliases xb)
//  4. flash_attn : balanced pairing slot s<7 -> {s,13-s}, s==7 -> {14};
//                  straight loop, exp2, diag-only mask, cvt_pk, setprio.
//                  P tiles fp16 -> pscr coalesced; cst = 1/lsum [bh][i].
//  5. attn_mean_p: streaming mean: read pscr (8 heads) * rinv -> fp32.
//  6. out_gemm   : ctx @ woT + bo -> fp32, 128x128 BK=64 2-phase dbuf.

typedef unsigned short ushort_t;
typedef __attribute__((ext_vector_type(8))) short short8;
typedef __attribute__((ext_vector_type(4))) float floatx4;
typedef __attribute__((ext_vector_type(2))) __fp16 half2v;

#define NB 32
#define NS 480
#define ND 512
#define NH 8
#define NDK 64
#define MAXLEN 500
#define PSTR 36   // sP row stride (ushorts): b128 frag reads <=2-way bank alias
#define SCL 0.18033688f  // 0.125 * log2(e)

__device__ __forceinline__ ushort_t f2bf(float f) {
  union { float f; unsigned u; } v; v.f = f;
  unsigned r = v.u + 0x7FFFu + ((v.u >> 16) & 1u);
  return (ushort_t)(r >> 16);
}

#define GLOAD_LDS16(g, l)                                                      \
  __builtin_amdgcn_global_load_lds(                                            \
      (const __attribute__((address_space(1))) void*)(g),                      \
      (__attribute__((address_space(3))) void*)(l), 16, 0, 0)

// ---------------------------------------------------------------- cvt_xw
// blocks [0,7680): x fp32->bf16 vectorized. blocks [7680,8704): w transpose.
__global__ __launch_bounds__(256)
void cvt_xw(const float* __restrict__ x, const float* __restrict__ wq,
            const float* __restrict__ wk, const float* __restrict__ wv,
            const float* __restrict__ wo, ushort_t* __restrict__ xb,
            ushort_t* __restrict__ wqT, ushort_t* __restrict__ wkT,
            ushort_t* __restrict__ wvT, ushort_t* __restrict__ woT) {
  __shared__ float t[32][33];
  const int bid = blockIdx.x;
  if (bid < 7680) {
    int idx = bid * 256 + threadIdx.x;
    float4 v = ((const float4*)x)[idx];
    ushort4 o;
    o.x = f2bf(v.x); o.y = f2bf(v.y); o.z = f2bf(v.z); o.w = f2bf(v.w);
    ((ushort4*)xb)[idx] = o;
    return;
  }
  const int q = bid - 7680;
  const int z = q >> 8;
  const float* w = (z == 0) ? wq : (z == 1) ? wk : (z == 2) ? wv : wo;
  ushort_t* wT = (z == 0) ? wqT : (z == 1) ? wkT : (z == 2) ? wvT : woT;
  int k0 = (q & 15) * 32, n0 = ((q >> 4) & 15) * 32;
  int tx = threadIdx.x & 31, ty = threadIdx.x >> 5;
#pragma unroll
  for (int yy = 0; yy < 4; ++yy)
    t[ty + yy * 8][tx] = w[(k0 + ty + yy * 8) * ND + n0 + tx];
  __syncthreads();
#pragma unroll
  for (int yy = 0; yy < 4; ++yy)
    wT[(n0 + ty + yy * 8) * ND + k0 + tx] = f2bf(t[tx][ty + yy * 8]);
}

// ---------------------------------------------------------------- cvt_rbt
__global__ void cvt_rbt(const float* __restrict__ rel_bias, float* __restrict__ rbt) {
  int kt = blockIdx.x, ib = blockIdx.y, h = blockIdx.z;
  int lm = threadIdx.x & 15, ii = threadIdx.x >> 4;
  int i = ib * 16 + ii;
  float f0 = rel_bias[((size_t)h * MAXLEN + i) * MAXLEN + kt * 32 + lm] * 1.44269504f;
  float f1 = rel_bias[((size_t)h * MAXLEN + i) * MAXLEN + kt * 32 + 16 + lm] * 1.44269504f;
  float2 o = {f0, f1};
  *(float2*)&rbt[(((size_t)h * 15 + kt) * NS + i) * 32 + 2 * lm] = o;
}

// ---------------------------------------------------------------- qkv_gemm
// z in {0,1}: q/k gemm (blocks x<120). z==2: V tiled gemm, b=x>>2.
// 2-phase double-buffered LDS staging.
__global__ __launch_bounds__(256)
void qkv_gemm(const ushort_t* __restrict__ xb,
              const ushort_t* __restrict__ wqT, const ushort_t* __restrict__ wkT,
              const ushort_t* __restrict__ wvT,
              const float* __restrict__ bq, const float* __restrict__ bk,
              const float* __restrict__ bv,
              ushort_t* __restrict__ qb, ushort_t* __restrict__ kb,
              ushort_t* __restrict__ vtil) {
  __shared__ __align__(16) ushort_t sA[2][128 * 64];
  __shared__ __align__(16) ushort_t sB[2][128 * 64];
  const int tid = threadIdx.x;
  const int wid = tid >> 6, lane = tid & 63;
  const int lm = lane & 15, quad = lane >> 4;
  const int wr = wid >> 1, wc = wid & 1;
  const int z = blockIdx.z;

  floatx4 zero4 = {0.f, 0.f, 0.f, 0.f};
  floatx4 acc[4][4];
#pragma unroll
  for (int i = 0; i < 4; ++i)
#pragma unroll
    for (int j = 0; j < 4; ++j) acc[i][j] = zero4;

  // staging geometry (shared by both paths)
  const int srow_ = tid >> 3, skc = tid & 7;
  const int skcs = skc ^ (srow_ & 7);

  if (z < 2) {
    if (blockIdx.x >= 120) return;
    const int row0 = blockIdx.x * 128;
    const int col0 = blockIdx.y * 128;
    const ushort_t* Bt = (z == 0) ? wqT : wkT;
    const float* bias = (z == 0) ? bq : bk;

    // prologue: stage k0=0 into buf 0
#pragma unroll
    for (int c = 0; c < 4; ++c) {
      int row = c * 32 + srow_;
      GLOAD_LDS16(xb + (row0 + row) * ND + skcs * 8, &sA[0][(c * 256 + wid * 64) * 8]);
      GLOAD_LDS16(Bt + (col0 + row) * ND + skcs * 8, &sB[0][(c * 256 + wid * 64) * 8]);
    }
    __syncthreads();

    int buf = 0;
    for (int t = 0; t < 8; ++t) {
      if (t < 7) {
        int k0n = (t + 1) * 64;
#pragma unroll
        for (int c = 0; c < 4; ++c) {
          int row = c * 32 + srow_;
          GLOAD_LDS16(xb + (row0 + row) * ND + k0n + skcs * 8,
                      &sA[buf ^ 1][(c * 256 + wid * 64) * 8]);
          GLOAD_LDS16(Bt + (col0 + row) * ND + k0n + skcs * 8,
                      &sB[buf ^ 1][(c * 256 + wid * 64) * 8]);
        }
      }
#pragma unroll
      for (int h2 = 0; h2 < 2; ++h2) {
        short8 a[4], b[4];
#pragma unroll
        for (int i = 0; i < 4; ++i) {
          int row = wr * 64 + i * 16 + lm;
          a[i] = *(const short8*)&sA[buf][row * 64 + (((h2 << 2) | quad) ^ (lm & 7)) * 8];
        }
#pragma unroll
        for (int j = 0; j < 4; ++j) {
          int row = wc * 64 + j * 16 + lm;
          b[j] = *(const short8*)&sB[buf][row * 64 + (((h2 << 2) | quad) ^ (lm & 7)) * 8];
        }
#pragma unroll
        for (int i = 0; i < 4; ++i)
#pragma unroll
          for (int j = 0; j < 4; ++j)
            acc[i][j] = __builtin_amdgcn_mfma_f32_16x16x32_bf16(a[i], b[j], acc[i][j], 0, 0, 0);
      }
      __syncthreads();
      buf ^= 1;
    }

    float bsv[4];
#pragma unroll
    for (int j = 0; j < 4; ++j) bsv[j] = bias[col0 + wc * 64 + j * 16 + lm];

#pragma unroll
    for (int i = 0; i < 4; ++i)
#pragma unroll
      for (int j = 0; j < 4; ++j)
#pragma unroll
        for (int r = 0; r < 4; ++r) {
          int m = row0 + wr * 64 + i * 16 + quad * 4 + r;
          int n = col0 + wc * 64 + j * 16 + lm;
          float val = acc[i][j][r] + bsv[j];
          int bb = m / NS, s = m - bb * NS;
          int h = n >> 6, d = n & 63;
          ushort_t o = f2bf(val);
          if (z == 0) qb[((bb * NH + h) * NS + s) * NDK + d] = o;
          else        kb[((bb * NH + h) * NS + s) * NDK + d] = o;
        }
  } else {
    const int b = blockIdx.x >> 2;
    const int row0 = (blockIdx.x & 3) * 128;  // dd
    const int col0 = blockIdx.y * 128;        // s
    const ushort_t* xbb = xb + (size_t)b * NS * ND;

#pragma unroll
    for (int c = 0; c < 4; ++c) {
      int row = c * 32 + srow_;
      GLOAD_LDS16(wvT + (row0 + row) * ND + skcs * 8, &sA[0][(c * 256 + wid * 64) * 8]);
      int sr = min(col0 + row, NS - 1);
      GLOAD_LDS16(xbb + sr * ND + skcs * 8, &sB[0][(c * 256 + wid * 64) * 8]);
    }
    __syncthreads();

    int buf = 0;
    for (int t = 0; t < 8; ++t) {
      if (t < 7) {
        int k0n = (t + 1) * 64;
#pragma unroll
        for (int c = 0; c < 4; ++c) {
          int row = c * 32 + srow_;
          GLOAD_LDS16(wvT + (row0 + row) * ND + k0n + skcs * 8,
                      &sA[buf ^ 1][(c * 256 + wid * 64) * 8]);
          int sr = min(col0 + row, NS - 1);
          GLOAD_LDS16(xbb + sr * ND + k0n + skcs * 8,
                      &sB[buf ^ 1][(c * 256 + wid * 64) * 8]);
        }
      }
#pragma unroll
      for (int h2 = 0; h2 < 2; ++h2) {
        short8 a[4], b2[4];
#pragma unroll
        for (int i = 0; i < 4; ++i) {
          int row = wr * 64 + i * 16 + lm;
          a[i] = *(const short8*)&sA[buf][row * 64 + (((h2 << 2) | quad) ^ (lm & 7)) * 8];
        }
#pragma unroll
        for (int j = 0; j < 4; ++j) {
          int row = wc * 64 + j * 16 + lm;
          b2[j] = *(const short8*)&sB[buf][row * 64 + (((h2 << 2) | quad) ^ (lm & 7)) * 8];
        }
#pragma unroll
        for (int i = 0; i < 4; ++i)
#pragma unroll
          for (int j = 0; j < 4; ++j)
            acc[i][j] = __builtin_amdgcn_mfma_f32_16x16x32_bf16(a[i], b2[j], acc[i][j], 0, 0, 0);
      }
      __syncthreads();
      buf ^= 1;
    }

#pragma unroll
    for (int i = 0; i < 4; ++i)
#pragma unroll
      for (int r = 0; r < 4; ++r) {
        int m = row0 + wr * 64 + i * 16 + quad * 4 + r;  // dd = h*64 + d
        float bias = bv[m];
#pragma unroll
        for (int j = 0; j < 4; ++j) {
          int n = col0 + wc * 64 + j * 16 + lm;  // s
          if (n < NS) {
            size_t idx = (((size_t)b * NH + (m >> 6)) * 15 + (n >> 5)) * 2048 +
                         (m & 63) * 32 + (n & 31);
            vtil[idx] = f2bf(acc[i][j][r] + bias);
          }
        }
      }
  }
}

// ---------------------------------------------------------------- flash_attn
// grid (256 bh, 2). slot = y*4+wid in 0..7; slot<7 -> tiles {slot, 13-slot},
// slot==7 -> {14}: every wave runs exactly 15 kt-iterations (load-balanced).
__global__ __launch_bounds__(256)
void flash_attn(const ushort_t* __restrict__ qb, const ushort_t* __restrict__ kb,
                const ushort_t* __restrict__ vtil, const float* __restrict__ rbt,
                ushort_t* __restrict__ ctxb, float* __restrict__ cst,
                uint4* __restrict__ pscr) {
  const int bh = blockIdx.x;
  const int b = bh >> 3, h = bh & 7;
  const int tid = threadIdx.x;
  const int wid = tid >> 6, lane = tid & 63;
  const int lm = lane & 15, quad = lane >> 4;

  __shared__ __align__(16) ushort_t sP[4][32 * PSTR];

  const int slot = blockIdx.y * 4 + wid;  // 0..7
  const int tA = (slot == 7) ? 14 : slot;
  const int tB = (slot == 7) ? -1 : 13 - slot;

  const ushort_t* qh = qb + (size_t)bh * NS * NDK;
  const ushort_t* kh = kb + (size_t)bh * NS * NDK;
  const ushort_t* vb = vtil + (size_t)bh * 15 * 2048;
  const float* rb = rbt + (size_t)h * 15 * NS * 32;

#pragma unroll 1
  for (int ti = 0; ti < 2; ++ti) {
    const int t = (ti == 0) ? tA : tB;
    if (t < 0) break;
    const int nkt = t + 1;
    uint4* pp = pscr + ((size_t)(bh * 120 + (t * (t + 1)) / 2)) * 128 + lane;

    short8 aq[2][2];
#pragma unroll
    for (int g = 0; g < 2; ++g) {
      aq[g][0] = *(const short8*)&qh[(t * 32 + g * 16 + lm) * NDK + quad * 8];
      aq[g][1] = *(const short8*)&qh[(t * 32 + g * 16 + lm) * NDK + 32 + quad * 8];
    }

    float lsum[2][4];
    floatx4 O[2][4];
    floatx4 zero4 = {0.f, 0.f, 0.f, 0.f};
#pragma unroll
    for (int g = 0; g < 2; ++g) {
#pragma unroll
      for (int r = 0; r < 4; ++r) lsum[g][r] = 0.f;
#pragma unroll
      for (int jd = 0; jd < 4; ++jd) O[g][jd] = zero4;
    }

    for (int kt = 0; kt < nkt; ++kt) {
      const int kvA = kt * 32 + lm;
      const int kvB = kvA + 16;
      short8 bkA0 = *(const short8*)&kh[kvA * NDK + quad * 8];
      short8 bkA1 = *(const short8*)&kh[kvA * NDK + 32 + quad * 8];
      short8 bkB0 = *(const short8*)&kh[kvB * NDK + quad * 8];
      short8 bkB1 = *(const short8*)&kh[kvB * NDK + 32 + quad * 8];
      short8 bv2[4];
#pragma unroll
      for (int jd = 0; jd < 4; ++jd)
        bv2[jd] = *(const short8*)&vb[kt * 2048 + (jd * 16 + lm) * 32 + quad * 8];
      float2 bb[2][4];
#pragma unroll
      for (int g = 0; g < 2; ++g)
#pragma unroll
        for (int r = 0; r < 4; ++r) {
          int i = t * 32 + g * 16 + quad * 4 + r;
          bb[g][r] = *(const float2*)&rb[((size_t)kt * NS + i) * 32 + 2 * lm];
        }

      floatx4 sA[2], sB[2];
      __builtin_amdgcn_s_setprio(1);
#pragma unroll
      for (int g = 0; g < 2; ++g) {
        floatx4 s = zero4;
        s = __builtin_amdgcn_mfma_f32_16x16x32_bf16(aq[g][0], bkA0, s, 0, 0, 0);
        s = __builtin_amdgcn_mfma_f32_16x16x32_bf16(aq[g][1], bkA1, s, 0, 0, 0);
        sA[g] = s;
        s = zero4;
        s = __builtin_amdgcn_mfma_f32_16x16x32_bf16(aq[g][0], bkB0, s, 0, 0, 0);
        s = __builtin_amdgcn_mfma_f32_16x16x32_bf16(aq[g][1], bkB1, s, 0, 0, 0);
        sB[g] = s;
      }
      __builtin_amdgcn_s_setprio(0);

      const bool diag = (kt == t);  // wave-uniform
#pragma unroll
      for (int g = 0; g < 2; ++g) {
        unsigned pw[4];
#pragma unroll
        for (int r = 0; r < 4; ++r) {
          float p0 = __builtin_amdgcn_exp2f(fmaf(sA[g][r], SCL, bb[g][r].x));
          float p1 = __builtin_amdgcn_exp2f(fmaf(sB[g][r], SCL, bb[g][r].y));
          if (diag) {
            int i = t * 32 + g * 16 + quad * 4 + r;
            if (kvA > i) p0 = 0.f;
            if (kvB > i) p1 = 0.f;
          }
          lsum[g][r] += p0 + p1;
          unsigned pk;
          asm("v_cvt_pk_bf16_f32 %0, %1, %2" : "=v"(pk) : "v"(p0), "v"(p1));
          sP[wid][(g * 16 + quad * 4 + r) * PSTR + lm] = (ushort_t)(pk & 0xffffu);
          sP[wid][(g * 16 + quad * 4 + r) * PSTR + 16 + lm] = (ushort_t)(pk >> 16);
          half2v hp = __builtin_amdgcn_cvt_pkrtz(p0, p1);
          pw[r] = *(unsigned*)&hp;
        }
        uint4 pq = {pw[0], pw[1], pw[2], pw[3]};
        pp[(size_t)kt * 128 + g * 64] = pq;  // fire-and-forget, 1KB/instr
      }

      __builtin_amdgcn_s_setprio(1);
#pragma unroll
      for (int g = 0; g < 2; ++g) {
        short8 ap = *(const short8*)&sP[wid][(g * 16 + lm) * PSTR + quad * 8];
#pragma unroll
        for (int jd = 0; jd < 4; ++jd)
          O[g][jd] = __builtin_amdgcn_mfma_f32_16x16x32_bf16(ap, bv2[jd], O[g][jd], 0, 0, 0);
      }
      __builtin_amdgcn_s_setprio(0);
    }

#pragma unroll
    for (int off = 1; off < 16; off <<= 1)
#pragma unroll
      for (int g = 0; g < 2; ++g)
#pragma unroll
        for (int r = 0; r < 4; ++r) lsum[g][r] += __shfl_xor(lsum[g][r], off, 64);

#pragma unroll
    for (int g = 0; g < 2; ++g) {
      float rinv[4];
#pragma unroll
      for (int r = 0; r < 4; ++r) rinv[r] = 1.f / lsum[g][r];
#pragma unroll
      for (int jd = 0; jd < 4; ++jd)
#pragma unroll
        for (int r = 0; r < 4; ++r) {
          int i = t * 32 + g * 16 + quad * 4 + r;
          ctxb[((size_t)b * NS + i) * ND + h * NDK + jd * 16 + lm] =
              f2bf(O[g][jd][r] * rinv[r]);
        }
      if (lm == 0) {
#pragma unroll
        for (int r = 0; r < 4; ++r) {
          int i = t * 32 + g * 16 + quad * 4 + r;
          cst[(size_t)bh * NS + i] = rinv[r];
        }
      }
    }
  }
}

// ---------------------------------------------------------------- attn_mean_p
__global__ __launch_bounds__(64)
void attn_mean_p(const uint4* __restrict__ pscr, const float* __restrict__ cst,
                 float* __restrict__ am) {
  const int b = blockIdx.x, t = blockIdx.y, kt = blockIdx.z;
  const int lane = threadIdx.x;
  const int lm = lane & 15, quad = lane >> 4;
  float* outp = am + ((size_t)b * NS + t * 32) * NS + (size_t)kt * 32;
  if (kt > t) {
#pragma unroll
    for (int g = 0; g < 2; ++g)
#pragma unroll
      for (int r = 0; r < 4; ++r) {
        int row = g * 16 + quad * 4 + r;
        outp[(size_t)row * NS + lm] = 0.f;
        outp[(size_t)row * NS + 16 + lm] = 0.f;
      }
    return;
  }
  const int m = (t * (t + 1)) / 2 + kt;
  float a0[2][4], a1[2][4];
#pragma unroll
  for (int g = 0; g < 2; ++g)
#pragma unroll
    for (int r = 0; r < 4; ++r) { a0[g][r] = 0.f; a1[g][r] = 0.f; }

#pragma unroll
  for (int h = 0; h < NH; ++h) {
    const uint4* pp = pscr + ((size_t)(b * NH + h) * 120 + m) * 128 + lane;
    uint4 q0 = pp[0];        // g=0: rows quad*4..+3 of 0..15, cols lm/16+lm
    uint4 q1 = pp[64];       // g=1
    unsigned pu[8] = {q0.x, q0.y, q0.z, q0.w, q1.x, q1.y, q1.z, q1.w};
    const float* cp = cst + (size_t)(b * NH + h) * NS + t * 32 + quad * 4;
    float4 rv0 = *(const float4*)cp;
    float4 rv1 = *(const float4*)(cp + 16);
    float rv[8] = {rv0.x, rv0.y, rv0.z, rv0.w, rv1.x, rv1.y, rv1.z, rv1.w};
#pragma unroll
    for (int g = 0; g < 2; ++g)
#pragma unroll
      for (int r = 0; r < 4; ++r) {
        half2v hp = *(half2v*)&pu[g * 4 + r];
        a0[g][r] = fmaf((float)hp.x, rv[g * 4 + r], a0[g][r]);
        a1[g][r] = fmaf((float)hp.y, rv[g * 4 + r], a1[g][r]);
      }
  }

#pragma unroll
  for (int g = 0; g < 2; ++g)
#pragma unroll
    for (int r = 0; r < 4; ++r) {
      int row = g * 16 + quad * 4 + r;
      outp[(size_t)row * NS + lm] = a0[g][r] * 0.125f;
      outp[(size_t)row * NS + 16 + lm] = a1[g][r] * 0.125f;
    }
}

// ---------------------------------------------------------------- out_gemm
// ctx @ woT + bo, 2-phase double-buffered LDS staging.
__global__ __launch_bounds__(256)
void out_gemm(const ushort_t* __restrict__ ctxb, const ushort_t* __restrict__ woT,
              const float* __restrict__ bo, float* __restrict__ out) {
  __shared__ __align__(16) ushort_t sA[2][128 * 64];
  __shared__ __align__(16) ushort_t sB[2][128 * 64];
  const int tid = threadIdx.x;
  const int wid = tid >> 6, lane = tid & 63;
  const int lm = lane & 15, quad = lane >> 4;
  const int wr = wid >> 1, wc = wid & 1;
  const int row0 = blockIdx.x * 128;
  const int col0 = blockIdx.y * 128;
  const int srow_ = tid >> 3, skc = tid & 7;
  const int skcs = skc ^ (srow_ & 7);

  floatx4 zero4 = {0.f, 0.f, 0.f, 0.f};
  floatx4 acc[4][4];
#pragma unroll
  for (int i = 0; i < 4; ++i)
#pragma unroll
    for (int j = 0; j < 4; ++j) acc[i][j] = zero4;

#pragma unroll
  for (int c = 0; c < 4; ++c) {
    int row = c * 32 + srow_;
    GLOAD_LDS16(ctxb + (row0 + row) * ND + skcs * 8, &sA[0][(c * 256 + wid * 64) * 8]);
    GLOAD_LDS16(woT + (col0 + row) * ND + skcs * 8, &sB[0][(c * 256 + wid * 64) * 8]);
  }
  __syncthreads();

  int buf = 0;
  for (int t = 0; t < 8; ++t) {
    if (t < 7) {
      int k0n = (t + 1) * 64;
#pragma unroll
      for (int c = 0; c < 4; ++c) {
        int row = c * 32 + srow_;
        GLOAD_LDS16(ctxb + (row0 + row) * ND + k0n + skcs * 8,
                    &sA[buf ^ 1][(c * 256 + wid * 64) * 8]);
        GLOAD_LDS16(woT + (col0 + row) * ND + k0n + skcs * 8,
                    &sB[buf ^ 1][(c * 256 + wid * 64) * 8]);
      }
    }
#pragma unroll
    for (int h2 = 0; h2 < 2; ++h2) {
      short8 a[4], b[4];
#pragma unroll
      for (int i = 0; i < 4; ++i) {
        int row = wr * 64 + i * 16 + lm;
        a[i] = *(const short8*)&sA[buf][row * 64 + (((h2 << 2) | quad) ^ (lm & 7)) * 8];
      }
#pragma unroll
      for (int j = 0; j < 4; ++j) {
        int row = wc * 64 + j * 16 + lm;
        b[j] = *(const short8*)&sB[buf][row * 64 + (((h2 << 2) | quad) ^ (lm & 7)) * 8];
      }
#pragma unroll
      for (int i = 0; i < 4; ++i)
#pragma unroll
        for (int j = 0; j < 4; ++j)
          acc[i][j] = __builtin_amdgcn_mfma_f32_16x16x32_bf16(a[i], b[j], acc[i][j], 0, 0, 0);
    }
    __syncthreads();
    buf ^= 1;
  }

  float bsv[4];
#pragma unroll
  for (int j = 0; j < 4; ++j) bsv[j] = bo[col0 + wc * 64 + j * 16 + lm];

#pragma unroll
  for (int i = 0; i < 4; ++i)
#pragma unroll
    for (int j = 0; j < 4; ++j)
#pragma unroll
      for (int r = 0; r < 4; ++r) {
        int m = row0 + wr * 64 + i * 16 + quad * 4 + r;
        int n = col0 + wc * 64 + j * 16 + lm;
        out[m * ND + n] = acc[i][j][r] + bsv[j];
      }
}

// ---------------------------------------------------------------- launch
extern "C" void kernel_launch(void* const* d_in, const int* in_sizes, int n_in,
                              void* d_out, int out_size, void* d_ws, size_t ws_size,
                              hipStream_t stream) {
  const float* x  = (const float*)d_in[0];
  const float* wq = (const float*)d_in[1];
  const float* bq = (const float*)d_in[2];
  const float* wk = (const float*)d_in[3];
  const float* bk = (const float*)d_in[4];
  const float* wv = (const float*)d_in[5];
  const float* bv = (const float*)d_in[6];
  const float* wo = (const float*)d_in[7];
  const float* bo = (const float*)d_in[8];
  const float* rel_bias = (const float*)d_in[9];

  char* w = (char*)d_ws;
  ushort_t* xb  = (ushort_t*)w;                       // 15,728,640 B
  ushort_t* wqT = (ushort_t*)(w + 15728640);          // 4 x 524,288 B
  ushort_t* wkT = wqT + 262144;
  ushort_t* wvT = wkT + 262144;
  ushort_t* woT = wvT + 262144;
  ushort_t* qb  = (ushort_t*)(w + 15728640 + 4 * 524288);
  ushort_t* kb  = qb + 7864320;
  ushort_t* vtil = kb + 7864320;                      // tiled V
  ushort_t* ctxb = vtil + 7864320;
  float* cstat = (float*)(w + 80740352);              // rinv [bh][i], 491,520 B
  uint4* pscr = (uint4*)(w + 81264640);               // P scratch, 62,914,560 B
  // rbt (14,745,600 B) aliases xb — xb is dead after qkv_gemm
  float* rbt = (float*)w;

  float* out0 = (float*)d_out;        // [32,480,512]
  float* attn_mean = out0 + 7864320;  // [32,480,480]

  cvt_xw<<<dim3(8704), dim3(256), 0, stream>>>(x, wq, wk, wv, wo, xb, wqT, wkT, wvT, woT);
  qkv_gemm<<<dim3(128, 4, 3), dim3(256), 0, stream>>>(xb, wqT, wkT, wvT, bq, bk, bv,
                                                      qb, kb, vtil);
  cvt_rbt<<<dim3(15, 30, 8), dim3(256), 0, stream>>>(rel_bias, rbt);
  flash_attn<<<dim3(256, 2), dim3(256), 0, stream>>>(qb, kb, vtil, rbt, ctxb, cstat, pscr);
  attn_mean_p<<<dim3(32, 15, 15), dim3(64), 0, stream>>>(pscr, cstat, attn_mean);
  out_gemm<<<dim3(120, 4), dim3(256), 0, stream>>>(ctxb, woT, bo, out0);
}